// Round 4
// baseline (1132.634 us; speedup 1.0000x reference)
//
#include <hip/hip_runtime.h>
#include <math.h>

#define B_ 16
#define T_ 12
#define N_ 1024
#define D_ 64
#define HS_ 16
#define HT_ 64
#define TT_ 192
#define BT_ 192

typedef _Float16 f16x2 __attribute__((ext_vector_type(2)));

__device__ __forceinline__ unsigned int pkrtz(float a, float b){
    auto r = __builtin_amdgcn_cvt_pkrtz(a, b);
    return __builtin_bit_cast(unsigned int, r);
}
__device__ __forceinline__ float fdot2u(unsigned int a, unsigned int b, float c){
    return __builtin_amdgcn_fdot2(__builtin_bit_cast(f16x2, a),
                                  __builtin_bit_cast(f16x2, b), c, false);
}
__device__ __forceinline__ float loF(unsigned int a){ f16x2 h = __builtin_bit_cast(f16x2, a); return (float)h.x; }
__device__ __forceinline__ float hiF(unsigned int a){ f16x2 h = __builtin_bit_cast(f16x2, a); return (float)h.y; }

__device__ __forceinline__ float lrelu_(float v){ return v > 0.f ? v : 0.01f*v; }
__device__ __forceinline__ float squash_sc(float sn){ return (sn/(1.f+sn))/(sqrtf(sn)+1e-8f); }

__device__ __forceinline__ float wredsum64(float v){
    #pragma unroll
    for (int mk = 1; mk < 64; mk <<= 1) v += __shfl_xor(v, mk, 64);
    return v;
}

// PT layout: f16 pair (n=2m, n=2m+1) of P[.][d], row d (stride 524 u32),
// column-quad mb stored at ((mb + (d>>3)) & 127)  -> uniform bank groups for b128.
__device__ __forceinline__ int ptq_idx(int d, int mb){
    return d*524 + 4*((mb + (d>>3)) & 127);
}

#define MEGA_LDS 155904
// PT:   [0, 134144)           64*524*4
// CLTP: [134144, 151552)      CL u32[16][256] / TP f32[4][16][68] / XST u32[8][256]
// VB:   [151552, 155904)      f32[16][68]

// NOTE __launch_bounds__(512, 1): with 152KB LDS this kernel is 1 block/CU
// regardless; min-waves=2 capped VGPRs at 128 and caused 2.25 GB of scratch
// spill traffic (round-3 counters). (512,1) lets the allocator use the full
// 256-VGPR budget that 2-waves/SIMD residency permits.
__global__ __launch_bounds__(512, 1) void k_mega(
        const float* __restrict__ x, const float* __restrict__ Wp,
        const float* __restrict__ bp, const float* __restrict__ teb,
        const float* __restrict__ adj,
        float* __restrict__ cout, float* __restrict__ sbuf){
    extern __shared__ char smem[];
    unsigned int* PT  = (unsigned int*)smem;
    unsigned int* CL  = (unsigned int*)(smem + 134144);
    float*        TP  = (float*)(smem + 134144);
    unsigned int* XST = (unsigned int*)(smem + 134144);
    float*        VB  = (float*)(smem + 151552);

    const int t  = threadIdx.x;
    const int bt = blockIdx.x;
    const int w  = t >> 6, l = t & 63;

    // ---- W rows (f16 packed) into regs: lane l holds W[l][2j],W[l][2j+1]
    unsigned int wpk[32];
    float bpd = bp[l];
    #pragma unroll
    for (int j = 0; j < 32; ++j){
        float2 w2 = *(const float2*)(Wp + l*64 + 2*j);
        wpk[j] = pkrtz(w2.x, w2.y);
    }

    // ---- dadj into regs; thread owns n0=2t, n1=2t+1
    float tl[16];
    #pragma unroll
    for (int e = 0; e < 16; ++e) tl[e] = teb[bt*16 + e];
    float dj0[16], dj1[16];
    #pragma unroll
    for (int h = 0; h < 16; ++h){
        float a0 = 0.f, a1 = 0.f;
        #pragma unroll
        for (int e = 0; e < 16; ++e){
            float2 av = *(const float2*)(adj + ((e*16 + h) << 10) + 2*t);
            a0 += tl[e]*av.x; a1 += tl[e]*av.y;
        }
        dj0[h] = a0; dj1[h] = a1;
    }

    // ---- P build: wave w -> rows [128w, 128w+128), batches of 8 rows
    {
        unsigned int* xst = XST + w*256;
        const float* xb = x + (size_t)bt * 65536;
        int half = l >> 5, j32 = l & 31;
        for (int bi = 0; bi < 16; ++bi){
            int r0 = w*128 + bi*8;
            #pragma unroll
            for (int rr = 0; rr < 8; rr += 2){
                int row = r0 + rr + half;
                float2 xv = *(const float2*)(xb + row*64 + 2*j32);
                xst[(rr + half)*32 + j32] = pkrtz(xv.x, xv.y);
            }
            unsigned int pk4[4];
            #pragma unroll
            for (int pp = 0; pp < 4; ++pp){
                float ya0 = 0.f, ya1 = 0.f, yb0 = 0.f, yb1 = 0.f;
                #pragma unroll
                for (int jq = 0; jq < 8; ++jq){
                    uint4 xa = *(uint4*)&xst[(2*pp)*32 + 4*jq];
                    uint4 xbq = *(uint4*)&xst[(2*pp+1)*32 + 4*jq];
                    ya0 = fdot2u(xa.x,  wpk[4*jq+0], ya0);
                    ya1 = fdot2u(xa.y,  wpk[4*jq+1], ya1);
                    ya0 = fdot2u(xa.z,  wpk[4*jq+2], ya0);
                    ya1 = fdot2u(xa.w,  wpk[4*jq+3], ya1);
                    yb0 = fdot2u(xbq.x, wpk[4*jq+0], yb0);
                    yb1 = fdot2u(xbq.y, wpk[4*jq+1], yb1);
                    yb0 = fdot2u(xbq.z, wpk[4*jq+2], yb0);
                    yb1 = fdot2u(xbq.w, wpk[4*jq+3], yb1);
                }
                float ya = bpd + ya0 + ya1;
                float yb = bpd + yb0 + yb1;
                float sna = wredsum64(ya*ya);
                float snb = wredsum64(yb*yb);
                pk4[pp] = pkrtz(ya*squash_sc(sna), yb*squash_sc(snb));
            }
            *(uint4*)&PT[ptq_idx(l, w*16 + bi)] = make_uint4(pk4[0], pk4[1], pk4[2], pk4[3]);
        }
    }
    __syncthreads();

    float bb0[16], bb1[16];
    #pragma unroll
    for (int h = 0; h < 16; ++h){ bb0[h] = 0.f; bb1[h] = 0.f; }
    float v1a = 0.f, v1b = 0.f;

    const int o = w & 1, G = w >> 1;   // h-oct, m-quarter

    #pragma unroll 1
    for (int pass = 0; pass < 5; ++pass){
        // --- per-thread softmax over h (for n0 and n1)
        float c0[16], c1[16];
        {
            float sv0[16], sv1[16];
            #pragma unroll
            for (int h = 0; h < 16; ++h){
                if (pass == 0){ sv0[h] = dj0[h]; sv1[h] = dj1[h]; }
                else if (pass < 4){ sv0[h] = bb0[h]; sv1[h] = bb1[h]; }
                else { sv0[h] = bb0[h] + dj0[h]; sv1[h] = bb1[h] + dj1[h]; }
            }
            float M0 = sv0[0], M1 = sv1[0];
            #pragma unroll
            for (int h = 1; h < 16; ++h){ M0 = fmaxf(M0, sv0[h]); M1 = fmaxf(M1, sv1[h]); }
            float S0 = 0.f, S1 = 0.f;
            #pragma unroll
            for (int h = 0; h < 16; ++h){
                c0[h] = __expf(sv0[h] - M0); S0 += c0[h];
                c1[h] = __expf(sv1[h] - M1); S1 += c1[h];
            }
            float i0 = 1.f/S0, i1 = 1.f/S1;
            #pragma unroll
            for (int h = 0; h < 16; ++h){ c0[h] *= i0; c1[h] *= i1; }
            if (pass == 4){
                #pragma unroll
                for (int h = 0; h < 16; ++h){
                    float2 cw; cw.x = c0[h]; cw.y = c1[h];
                    *(float2*)(cout + ((size_t)bt*16 + h)*1024 + 2*t) = cw;
                }
            }
        }

        // --- contraction t[h][d] = sum_n c[h][n] * P[n][d]
        float acc[8];
        #pragma unroll
        for (int hh = 0; hh < 8; ++hh) acc[hh] = 0.f;

        #pragma unroll
        for (int ch = 0; ch < 2; ++ch){
            __syncthreads();
            if ((t >> 8) == ch){
                int mc = t & 255;
                #pragma unroll
                for (int h = 0; h < 16; ++h) CL[h*256 + mc] = pkrtz(c0[h], c1[h]);
            }
            __syncthreads();
            #pragma unroll
            for (int q = 0; q < 16; ++q){
                int mcq = G*16 + q;
                int mb  = ch*64 + mcq;
                uint4 pt = *(uint4*)&PT[ptq_idx(l, mb)];
                #pragma unroll
                for (int hh = 0; hh < 8; ++hh){
                    uint4 cq = *(uint4*)&CL[(8*o + hh)*256 + 4*mcq];
                    acc[hh] = fdot2u(cq.x, pt.x, acc[hh]);
                    acc[hh] = fdot2u(cq.y, pt.y, acc[hh]);
                    acc[hh] = fdot2u(cq.z, pt.z, acc[hh]);
                    acc[hh] = fdot2u(cq.w, pt.w, acc[hh]);
                }
            }
        }
        __syncthreads();
        #pragma unroll
        for (int hh = 0; hh < 8; ++hh) TP[(G*16 + 8*o + hh)*68 + l] = acc[hh];
        __syncthreads();

        // --- owner wave w handles h = 2w, 2w+1 (lane = d)
        {
            float t0 = 0.f, t1 = 0.f;
            #pragma unroll
            for (int g2 = 0; g2 < 4; ++g2){
                t0 += TP[(g2*16 + 2*w    )*68 + l];
                t1 += TP[(g2*16 + 2*w + 1)*68 + l];
            }
            if (pass == 0){
                float sn0 = wredsum64(t0*t0), sn1 = wredsum64(t1*t1);
                v1a = t0*squash_sc(sn0); v1b = t1*squash_sc(sn1);
            } else if (pass < 4){
                float q0 = v1a*t0, q1 = v1b*t1;
                float sn0 = wredsum64(q0*q0), sn1 = wredsum64(q1*q1);
                VB[(2*w    )*68 + l] = q0*squash_sc(sn0);
                VB[(2*w + 1)*68 + l] = q1*squash_sc(sn1);
            } else {
                sbuf[((size_t)bt*16 + 2*w    )*64 + l] = t0;
                sbuf[((size_t)bt*16 + 2*w + 1)*64 + l] = t1;
            }
        }

        if (pass >= 1 && pass <= 3){
            __syncthreads();   // VB ready
            // bupd: thread owns m=t (rows n0=2t, n1=2t+1)
            int mb = t >> 2, off = t & 3;
            #pragma unroll
            for (int dq = 0; dq < 16; ++dq){
                float p0[4], p1[4];
                #pragma unroll
                for (int i = 0; i < 4; ++i){
                    int d = dq*4 + i;
                    unsigned int pv = PT[ptq_idx(d, mb) + off];
                    p0[i] = loF(pv); p1[i] = hiF(pv);
                }
                #pragma unroll
                for (int h = 0; h < 16; ++h){
                    float4 vb4 = *(float4*)&VB[h*68 + dq*4];
                    bb0[h] += vb4.x*p0[0] + vb4.y*p0[1] + vb4.z*p0[2] + vb4.w*p0[3];
                    bb1[h] += vb4.x*p1[0] + vb4.y*p1[1] + vb4.z*p1[2] + vb4.w*p1[3];
                }
            }
        }
    }
}

// dyn[b,h,k] = sum_e time_eb[b,e]*t_adj[e,h,k]
__global__ __launch_bounds__(192) void k_dyn(const float* __restrict__ timeb,
        const float* __restrict__ tadj, float* __restrict__ dyn){
    int b = blockIdx.x, h = blockIdx.y, k = threadIdx.x;
    float acc = 0.f;
    #pragma unroll
    for (int e = 0; e < 16; ++e)
        acc += timeb[b*16+e]*tadj[((size_t)e*HT_+h)*TT_ + k];
    dyn[((size_t)b*HT_+h)*TT_ + k] = acc;
}

// tem[b,h,d] = lrelu( sum_k dyn[b,h,k]*(s[b,k,d] + mask[k>>4]) )  grid (16,16) x 256
__global__ __launch_bounds__(256) void k_tem(const float* __restrict__ dyn,
        const float* __restrict__ sbuf, float* __restrict__ tem){
    int b = blockIdx.x, hg = blockIdx.y;
    int w = threadIdx.x >> 6, l = threadIdx.x & 63;
    int h = hg*4 + w;
    const float* dr = dyn + ((size_t)b*HT_ + h)*TT_;
    const float* sb = sbuf + (size_t)b*TT_*64;
    float a0 = 0.f, a1 = 0.f;
    #pragma unroll 4
    for (int k = 0; k < TT_; k += 2){
        float m0 = (float)((k>>4)+1) * (1.f/12.f);
        float m1 = (float)(((k+1)>>4)+1) * (1.f/12.f);
        a0 += dr[k]   * (sb[(size_t)k*64 + l]     + m0);
        a1 += dr[k+1] * (sb[(size_t)(k+1)*64 + l] + m1);
    }
    float a = a0 + a1;
    tem[((size_t)b*HT_ + h)*64 + l] = lrelu_(a);
}

// ret=lrelu(sum_h dyn*tem)+s; v2=squash(ret)   grid (16,48) x 256
__global__ __launch_bounds__(256) void k_retv2(const float* __restrict__ dyn,
        const float* __restrict__ temb, const float* __restrict__ sbuf,
        float* __restrict__ v2){
    int b = blockIdx.x, kg = blockIdx.y;
    int w = threadIdx.x >> 6, l = threadIdx.x & 63;
    int k = kg*4 + w;
    const float* tb = temb + (size_t)b*HT_*64;
    float a0 = 0.f, a1 = 0.f;
    #pragma unroll 4
    for (int h = 0; h < HT_; h += 2){
        a0 += dyn[((size_t)b*HT_ + h  )*TT_ + k] * tb[(size_t)h*64 + l];
        a1 += dyn[((size_t)b*HT_ + h+1)*TT_ + k] * tb[(size_t)(h+1)*64 + l];
    }
    float a = lrelu_(a0 + a1);
    float r = a + sbuf[((size_t)b*TT_ + k)*64 + l];
    float sn = wredsum64(r*r);
    v2[((size_t)b*TT_ + k)*64 + l] = r*squash_sc(sn);
}

// recon (f16 packed pairs): rec[bt,n,d] = sum_h c[bt,h,n]*v2[bt,h,d]  grid (192,8) x 256
__global__ __launch_bounds__(256) void k_rec(const float* __restrict__ cbuf,
        const float* __restrict__ v2, unsigned int* __restrict__ recpk){
    __shared__ float vL[16*68];
    __shared__ float cL[16*132];
    int bt = blockIdx.x, nc = blockIdx.y;
    int t = threadIdx.x, l = t & 63, g = t >> 6;
    #pragma unroll
    for (int i = 0; i < 4; ++i){
        int idx = i*256 + t;
        vL[(idx>>6)*68 + (idx&63)] = v2[(size_t)bt*1024 + idx];
    }
    #pragma unroll
    for (int i = 0; i < 8; ++i){
        int idx = i*256 + t;   // h = idx>>7, j = idx&127
        cL[(idx>>7)*132 + (idx&127)] =
            cbuf[((size_t)bt*16 + (idx>>7))*1024 + nc*128 + (idx&127)];
    }
    __syncthreads();
    float vreg[16];
    #pragma unroll
    for (int h = 0; h < 16; ++h) vreg[h] = vL[h*68 + l];
    #pragma unroll 4
    for (int i = 0; i < 32; ++i){
        int nl = g + 4*i;
        float a = 0.f;
        #pragma unroll
        for (int h = 0; h < 16; ++h) a += cL[h*132 + nl]*vreg[h];
        float ap = __shfl_xor(a, 1, 64);
        if (!(l & 1))
            recpk[((size_t)bt*1024 + nc*128 + nl)*32 + (l>>1)] = pkrtz(a, ap);
    }
}

// out = lrelu(rec @ wsp[n] + bsp[n] + x)   grid 1024 x 256
__global__ __launch_bounds__(256) void k_final(const float* __restrict__ x,
        const float* __restrict__ ne, const float* __restrict__ wspa,
        const float* __restrict__ bspa, const unsigned int* __restrict__ recpk,
        float* __restrict__ out){
    __shared__ float wspL[64*68];
    __shared__ float bspL[64];
    int n = blockIdx.x, t = threadIdx.x, l = t & 63, g = t >> 6;
    float nl16[16];
    #pragma unroll
    for (int e = 0; e < 16; ++e) nl16[e] = ne[n*16 + e];
    #pragma unroll
    for (int j = 0; j < 16; ++j){
        int io = j*256 + t;
        float a = 0.f;
        #pragma unroll
        for (int e = 0; e < 16; ++e) a += nl16[e]*wspa[(size_t)e*4096 + io];
        wspL[(io>>6)*68 + (io&63)] = a;
    }
    if (t < 64){
        float a = 0.f;
        #pragma unroll
        for (int e = 0; e < 16; ++e) a += nl16[e]*bspa[e*64 + t];
        bspL[t] = a;
    }
    __syncthreads();
    unsigned int wr[32];
    #pragma unroll
    for (int ip = 0; ip < 32; ++ip)
        wr[ip] = pkrtz(wspL[(2*ip)*68 + l], wspL[(2*ip+1)*68 + l]);
    float bsp = bspL[l];
    #pragma unroll 2
    for (int i = 0; i < 48; ++i){
        int bt = g + 4*i;
        const uint4* rp = (const uint4*)(recpk + ((size_t)bt*1024 + n)*32);
        float o0 = bsp, o1 = 0.f;
        #pragma unroll
        for (int jj = 0; jj < 8; ++jj){
            uint4 rq = rp[jj];
            o0 = fdot2u(rq.x, wr[4*jj+0], o0);
            o1 = fdot2u(rq.y, wr[4*jj+1], o1);
            o0 = fdot2u(rq.z, wr[4*jj+2], o0);
            o1 = fdot2u(rq.w, wr[4*jj+3], o1);
        }
        size_t oidx = ((size_t)bt*1024 + n)*64 + l;
        float r = o0 + o1 + x[oidx];
        out[oidx] = lrelu_(r);
    }
}

extern "C" void kernel_launch(void* const* d_in, const int* in_sizes, int n_in,
                              void* d_out, int out_size, void* d_ws, size_t ws_size,
                              hipStream_t stream) {
    const float* x     = (const float*)d_in[0];
    const float* ne    = (const float*)d_in[1];
    const float* timeb = (const float*)d_in[2];
    const float* teb   = (const float*)d_in[3];
    const float* Wp    = (const float*)d_in[4];
    const float* bp    = (const float*)d_in[5];
    const float* tadj  = (const float*)d_in[6];
    const float* adj   = (const float*)d_in[7];
    const float* wspa  = (const float*)d_in[8];
    const float* bspa  = (const float*)d_in[9];

    float* out    = (float*)d_out;
    float* outc   = out  + (size_t)BT_*N_*64;      // c:   [BT,HS,N]
    float* outdyn = outc + (size_t)BT_*HS_*N_;     // dyn: [B,HT,TT]

    float* ws   = (float*)d_ws;
    float* sbuf = ws;                               // [BT,16,64]
    float* temb = sbuf + (size_t)BT_*HS_*64;        // [B,64,64]
    float* v2   = temb + (size_t)B_*HT_*64;         // [BT,16,64]
    unsigned int* recpk = (unsigned int*)(v2 + (size_t)BT_*HS_*64); // [BT,1024,32] u32

    (void)hipFuncSetAttribute((const void*)k_mega,
            hipFuncAttributeMaxDynamicSharedMemorySize, MEGA_LDS);

    k_mega<<<dim3(BT_), 512, MEGA_LDS, stream>>>(x, Wp, bp, teb, adj, outc, sbuf);
    k_dyn<<<dim3(B_, HT_), 192, 0, stream>>>(timeb, tadj, outdyn);
    k_tem<<<dim3(B_, 16), 256, 0, stream>>>(outdyn, sbuf, temb);
    k_retv2<<<dim3(B_, 48), 256, 0, stream>>>(outdyn, temb, sbuf, v2);
    k_rec<<<dim3(BT_, 8), 256, 0, stream>>>(outc, v2, recpk);
    k_final<<<dim3(N_), 256, 0, stream>>>(x, ne, wspa, bspa, recpk, out);
}

// Round 5
// 965.832 us; speedup vs baseline: 1.1727x; 1.1727x over previous
//
#include <hip/hip_runtime.h>
#include <math.h>

#define B_ 16
#define T_ 12
#define N_ 1024
#define D_ 64
#define HS_ 16
#define HT_ 64
#define TT_ 192
#define BT_ 192

typedef _Float16 f16x2 __attribute__((ext_vector_type(2)));

__device__ __forceinline__ unsigned int pkrtz(float a, float b){
    auto r = __builtin_amdgcn_cvt_pkrtz(a, b);
    return __builtin_bit_cast(unsigned int, r);
}
__device__ __forceinline__ float fdot2u(unsigned int a, unsigned int b, float c){
    return __builtin_amdgcn_fdot2(__builtin_bit_cast(f16x2, a),
                                  __builtin_bit_cast(f16x2, b), c, false);
}
__device__ __forceinline__ float loF(unsigned int a){ f16x2 h = __builtin_bit_cast(f16x2, a); return (float)h.x; }
__device__ __forceinline__ float hiF(unsigned int a){ f16x2 h = __builtin_bit_cast(f16x2, a); return (float)h.y; }

__device__ __forceinline__ float lrelu_(float v){ return v > 0.f ? v : 0.01f*v; }
__device__ __forceinline__ float squash_sc(float sn){ return (sn/(1.f+sn))/(sqrtf(sn)+1e-8f); }

__device__ __forceinline__ float wredsum64(float v){
    #pragma unroll
    for (int mk = 1; mk < 64; mk <<= 1) v += __shfl_xor(v, mk, 64);
    return v;
}

// PT layout: f16 pair (n=2m, n=2m+1) of P[.][d]; row d (stride 512 u32),
// XOR bank swizzle: quad mb at byte-column (4*mb) ^ ((d&7)<<2) -> 8 distinct
// quad-groups across lanes for b128 reads (uniform, conflict-free floor).
__device__ __forceinline__ int ptq_idx(int d, int mb){
    return d*512 + ((4*mb) ^ ((d & 7) << 2));
}

#define MEGA_LDS 163840
// PT:  [0, 131072)            64 rows x 512 u32
// CL:  [131072, 163840)       u32[16][512]  (c as f16 n-pairs)
// TP:  [131072, 148480)       f32[64][68]   (overlaps CL; time-disjoint)
// VB:  [148480, 152832)       f32[16][68]   (overlaps CL; time-disjoint)
// XST: [131072, 139264)       u32[8][256]   (P-build only)

// VGPR note (round-3/4 counters): backend pins this 512-thread kernel at 128
// VGPRs regardless of launch_bounds' 2nd arg; with dadj recomputed (not
// stored) and c staged to LDS right after softmax, peak live ~90 regs ->
// no spill within the 128 cap.
__global__ __launch_bounds__(512, 1) void k_mega(
        const float* __restrict__ x, const float* __restrict__ Wp,
        const float* __restrict__ bp, const float* __restrict__ teb,
        const float* __restrict__ adj,
        float* __restrict__ cout, float* __restrict__ sbuf){
    extern __shared__ char smem[];
    unsigned int* PT  = (unsigned int*)smem;
    unsigned int* CL  = (unsigned int*)(smem + 131072);
    float*        TP  = (float*)(smem + 131072);
    unsigned int* XST = (unsigned int*)(smem + 131072);
    float*        VB  = (float*)(smem + 148480);

    const int t  = threadIdx.x;
    const int bt = blockIdx.x;
    const int w  = t >> 6, l = t & 63;
    const int o  = w & 1, G = w >> 1;   // h-oct, m-quarter for MAC

    // ---- P build: W rows (f16 packed) in regs; wave w -> rows [128w,128w+128)
    {
        unsigned int wpk[32];
        float bpd = bp[l];
        #pragma unroll
        for (int j = 0; j < 32; ++j){
            float2 w2 = *(const float2*)(Wp + l*64 + 2*j);
            wpk[j] = pkrtz(w2.x, w2.y);
        }
        unsigned int* xst = XST + w*256;
        const float* xb = x + (size_t)bt * 65536;
        int half = l >> 5, j32 = l & 31;
        for (int bi = 0; bi < 16; ++bi){
            int r0 = w*128 + bi*8;
            #pragma unroll
            for (int rr = 0; rr < 8; rr += 2){
                int row = r0 + rr + half;
                float2 xv = *(const float2*)(xb + row*64 + 2*j32);
                xst[(rr + half)*32 + j32] = pkrtz(xv.x, xv.y);
            }
            unsigned int pk4[4];
            #pragma unroll
            for (int pp = 0; pp < 4; ++pp){
                float ya0 = 0.f, ya1 = 0.f, yb0 = 0.f, yb1 = 0.f;
                #pragma unroll
                for (int jq = 0; jq < 8; ++jq){
                    uint4 xa  = *(uint4*)&xst[(2*pp)*32 + 4*jq];
                    uint4 xbq = *(uint4*)&xst[(2*pp+1)*32 + 4*jq];
                    ya0 = fdot2u(xa.x,  wpk[4*jq+0], ya0);
                    ya1 = fdot2u(xa.y,  wpk[4*jq+1], ya1);
                    ya0 = fdot2u(xa.z,  wpk[4*jq+2], ya0);
                    ya1 = fdot2u(xa.w,  wpk[4*jq+3], ya1);
                    yb0 = fdot2u(xbq.x, wpk[4*jq+0], yb0);
                    yb1 = fdot2u(xbq.y, wpk[4*jq+1], yb1);
                    yb0 = fdot2u(xbq.z, wpk[4*jq+2], yb0);
                    yb1 = fdot2u(xbq.w, wpk[4*jq+3], yb1);
                }
                float ya = bpd + ya0 + ya1;
                float yb = bpd + yb0 + yb1;
                float sna = wredsum64(ya*ya);
                float snb = wredsum64(yb*yb);
                pk4[pp] = pkrtz(ya*squash_sc(sna), yb*squash_sc(snb));
            }
            *(uint4*)&PT[ptq_idx(l, w*16 + bi)] = make_uint4(pk4[0], pk4[1], pk4[2], pk4[3]);
        }
    }

    float bb0[16], bb1[16];
    #pragma unroll
    for (int h = 0; h < 16; ++h){ bb0[h] = 0.f; bb1[h] = 0.f; }
    float v1a = 0.f, v1b = 0.f;

    #pragma unroll 1
    for (int pass = 0; pass < 5; ++pass){
        // --- logits into c0/c1 (dadj recomputed at pass 0 and 4; adj is L2-hot)
        float c0[16], c1[16];
        if (pass == 0 || pass == 4){
            float tl[16];
            #pragma unroll
            for (int e = 0; e < 16; ++e) tl[e] = teb[bt*16 + e];
            #pragma unroll
            for (int h = 0; h < 16; ++h){
                float a0 = 0.f, a1 = 0.f;
                #pragma unroll
                for (int e = 0; e < 16; ++e){
                    float2 av = *(const float2*)(adj + ((e*16 + h) << 10) + 2*t);
                    a0 += tl[e]*av.x; a1 += tl[e]*av.y;
                }
                c0[h] = a0 + (pass == 4 ? bb0[h] : 0.f);
                c1[h] = a1 + (pass == 4 ? bb1[h] : 0.f);
            }
        } else {
            #pragma unroll
            for (int h = 0; h < 16; ++h){ c0[h] = bb0[h]; c1[h] = bb1[h]; }
        }
        // --- per-thread softmax over h (thread owns n0=2t, n1=2t+1)
        {
            float M0 = c0[0], M1 = c1[0];
            #pragma unroll
            for (int h = 1; h < 16; ++h){ M0 = fmaxf(M0, c0[h]); M1 = fmaxf(M1, c1[h]); }
            float S0 = 0.f, S1 = 0.f;
            #pragma unroll
            for (int h = 0; h < 16; ++h){
                c0[h] = __expf(c0[h] - M0); S0 += c0[h];
                c1[h] = __expf(c1[h] - M1); S1 += c1[h];
            }
            float i0 = 1.f/S0, i1 = 1.f/S1;
            #pragma unroll
            for (int h = 0; h < 16; ++h){ c0[h] *= i0; c1[h] *= i1; }
        }
        if (pass == 4){
            #pragma unroll
            for (int h = 0; h < 16; ++h){
                float2 cw; cw.x = c0[h]; cw.y = c1[h];
                *(float2*)(cout + ((size_t)bt*16 + h)*1024 + 2*t) = cw;
            }
        }

        // --- stage c to CL (barrier also protects prev pass's VB/PT readers)
        __syncthreads();
        #pragma unroll
        for (int h = 0; h < 16; ++h) CL[h*512 + t] = pkrtz(c0[h], c1[h]);
        __syncthreads();

        // --- MAC: t[h][d] = sum_n c[h][n]*P[n][d]; wave (o,G): h-oct x m-quarter
        float acc[8];
        #pragma unroll
        for (int hh = 0; hh < 8; ++hh) acc[hh] = 0.f;
        #pragma unroll 2
        for (int q = 0; q < 32; ++q){
            int mb = G*32 + q;
            uint4 pt = *(uint4*)&PT[ptq_idx(l, mb)];
            #pragma unroll
            for (int hh = 0; hh < 8; ++hh){
                uint4 cq = *(uint4*)&CL[(8*o + hh)*512 + 4*mb];
                acc[hh] = fdot2u(cq.x, pt.x, acc[hh]);
                acc[hh] = fdot2u(cq.y, pt.y, acc[hh]);
                acc[hh] = fdot2u(cq.z, pt.z, acc[hh]);
                acc[hh] = fdot2u(cq.w, pt.w, acc[hh]);
            }
        }
        __syncthreads();               // all CL reads done (TP overlaps CL)
        #pragma unroll
        for (int hh = 0; hh < 8; ++hh) TP[(G*16 + 8*o + hh)*68 + l] = acc[hh];
        __syncthreads();

        // --- owner wave w reduces quarters for h = 2w, 2w+1 (lane = d)
        {
            float t0 = 0.f, t1 = 0.f;
            #pragma unroll
            for (int g2 = 0; g2 < 4; ++g2){
                t0 += TP[(g2*16 + 2*w    )*68 + l];
                t1 += TP[(g2*16 + 2*w + 1)*68 + l];
            }
            if (pass == 0){
                float sn0 = wredsum64(t0*t0), sn1 = wredsum64(t1*t1);
                v1a = t0*squash_sc(sn0); v1b = t1*squash_sc(sn1);
            } else if (pass < 4){
                float q0 = v1a*t0, q1 = v1b*t1;
                float sn0 = wredsum64(q0*q0), sn1 = wredsum64(q1*q1);
                VB[(2*w    )*68 + l] = q0*squash_sc(sn0);
                VB[(2*w + 1)*68 + l] = q1*squash_sc(sn1);
            } else {
                sbuf[((size_t)bt*16 + 2*w    )*64 + l] = t0;
                sbuf[((size_t)bt*16 + 2*w + 1)*64 + l] = t1;
            }
        }

        if (pass >= 1 && pass <= 3){
            __syncthreads();           // VB ready
            // bupd: thread owns pair m=t (n0=2t, n1=2t+1)
            int mb = t >> 2, off = t & 3;
            #pragma unroll
            for (int dq = 0; dq < 16; ++dq){
                float p0[4], p1[4];
                #pragma unroll
                for (int i = 0; i < 4; ++i){
                    int d = dq*4 + i;
                    unsigned int pv = PT[ptq_idx(d, mb) + off];
                    p0[i] = loF(pv); p1[i] = hiF(pv);
                }
                #pragma unroll
                for (int h = 0; h < 16; ++h){
                    float4 vb4 = *(float4*)&VB[h*68 + dq*4];
                    bb0[h] += vb4.x*p0[0] + vb4.y*p0[1] + vb4.z*p0[2] + vb4.w*p0[3];
                    bb1[h] += vb4.x*p1[0] + vb4.y*p1[1] + vb4.z*p1[2] + vb4.w*p1[3];
                }
            }
        }
    }
}

// dyn[b,h,k] = sum_e time_eb[b,e]*t_adj[e,h,k]
__global__ __launch_bounds__(192) void k_dyn(const float* __restrict__ timeb,
        const float* __restrict__ tadj, float* __restrict__ dyn){
    int b = blockIdx.x, h = blockIdx.y, k = threadIdx.x;
    float acc = 0.f;
    #pragma unroll
    for (int e = 0; e < 16; ++e)
        acc += timeb[b*16+e]*tadj[((size_t)e*HT_+h)*TT_ + k];
    dyn[((size_t)b*HT_+h)*TT_ + k] = acc;
}

// tem[b,h,d] = lrelu( sum_k dyn[b,h,k]*(s[b,k,d] + mask[k>>4]) )  grid (16,16) x 256
__global__ __launch_bounds__(256) void k_tem(const float* __restrict__ dyn,
        const float* __restrict__ sbuf, float* __restrict__ tem){
    int b = blockIdx.x, hg = blockIdx.y;
    int w = threadIdx.x >> 6, l = threadIdx.x & 63;
    int h = hg*4 + w;
    const float* dr = dyn + ((size_t)b*HT_ + h)*TT_;
    const float* sb = sbuf + (size_t)b*TT_*64;
    float a0 = 0.f, a1 = 0.f;
    #pragma unroll 4
    for (int k = 0; k < TT_; k += 2){
        float m0 = (float)((k>>4)+1) * (1.f/12.f);
        float m1 = (float)(((k+1)>>4)+1) * (1.f/12.f);
        a0 += dr[k]   * (sb[(size_t)k*64 + l]     + m0);
        a1 += dr[k+1] * (sb[(size_t)(k+1)*64 + l] + m1);
    }
    float a = a0 + a1;
    tem[((size_t)b*HT_ + h)*64 + l] = lrelu_(a);
}

// ret=lrelu(sum_h dyn*tem)+s; v2=squash(ret)   grid (16,48) x 256
__global__ __launch_bounds__(256) void k_retv2(const float* __restrict__ dyn,
        const float* __restrict__ temb, const float* __restrict__ sbuf,
        float* __restrict__ v2){
    int b = blockIdx.x, kg = blockIdx.y;
    int w = threadIdx.x >> 6, l = threadIdx.x & 63;
    int k = kg*4 + w;
    const float* tb = temb + (size_t)b*HT_*64;
    float a0 = 0.f, a1 = 0.f;
    #pragma unroll 4
    for (int h = 0; h < HT_; h += 2){
        a0 += dyn[((size_t)b*HT_ + h  )*TT_ + k] * tb[(size_t)h*64 + l];
        a1 += dyn[((size_t)b*HT_ + h+1)*TT_ + k] * tb[(size_t)(h+1)*64 + l];
    }
    float a = lrelu_(a0 + a1);
    float r = a + sbuf[((size_t)b*TT_ + k)*64 + l];
    float sn = wredsum64(r*r);
    v2[((size_t)b*TT_ + k)*64 + l] = r*squash_sc(sn);
}

// recon (f16 packed pairs): rec[bt,n,d] = sum_h c[bt,h,n]*v2[bt,h,d]  grid (192,8) x 256
__global__ __launch_bounds__(256) void k_rec(const float* __restrict__ cbuf,
        const float* __restrict__ v2, unsigned int* __restrict__ recpk){
    __shared__ float vL[16*68];
    __shared__ float cL[16*132];
    int bt = blockIdx.x, nc = blockIdx.y;
    int t = threadIdx.x, l = t & 63, g = t >> 6;
    #pragma unroll
    for (int i = 0; i < 4; ++i){
        int idx = i*256 + t;
        vL[(idx>>6)*68 + (idx&63)] = v2[(size_t)bt*1024 + idx];
    }
    #pragma unroll
    for (int i = 0; i < 8; ++i){
        int idx = i*256 + t;   // h = idx>>7, j = idx&127
        cL[(idx>>7)*132 + (idx&127)] =
            cbuf[((size_t)bt*16 + (idx>>7))*1024 + nc*128 + (idx&127)];
    }
    __syncthreads();
    float vreg[16];
    #pragma unroll
    for (int h = 0; h < 16; ++h) vreg[h] = vL[h*68 + l];
    #pragma unroll 4
    for (int i = 0; i < 32; ++i){
        int nl = g + 4*i;
        float a = 0.f;
        #pragma unroll
        for (int h = 0; h < 16; ++h) a += cL[h*132 + nl]*vreg[h];
        float ap = __shfl_xor(a, 1, 64);
        if (!(l & 1))
            recpk[((size_t)bt*1024 + nc*128 + nl)*32 + (l>>1)] = pkrtz(a, ap);
    }
}

// out = lrelu(rec @ wsp[n] + bsp[n] + x)   grid 1024 x 256
__global__ __launch_bounds__(256) void k_final(const float* __restrict__ x,
        const float* __restrict__ ne, const float* __restrict__ wspa,
        const float* __restrict__ bspa, const unsigned int* __restrict__ recpk,
        float* __restrict__ out){
    __shared__ float wspL[64*68];
    __shared__ float bspL[64];
    int n = blockIdx.x, t = threadIdx.x, l = t & 63, g = t >> 6;
    float nl16[16];
    #pragma unroll
    for (int e = 0; e < 16; ++e) nl16[e] = ne[n*16 + e];
    #pragma unroll
    for (int j = 0; j < 16; ++j){
        int io = j*256 + t;
        float a = 0.f;
        #pragma unroll
        for (int e = 0; e < 16; ++e) a += nl16[e]*wspa[(size_t)e*4096 + io];
        wspL[(io>>6)*68 + (io&63)] = a;
    }
    if (t < 64){
        float a = 0.f;
        #pragma unroll
        for (int e = 0; e < 16; ++e) a += nl16[e]*bspa[e*64 + t];
        bspL[t] = a;
    }
    __syncthreads();
    unsigned int wr[32];
    #pragma unroll
    for (int ip = 0; ip < 32; ++ip)
        wr[ip] = pkrtz(wspL[(2*ip)*68 + l], wspL[(2*ip+1)*68 + l]);
    float bsp = bspL[l];
    #pragma unroll 2
    for (int i = 0; i < 48; ++i){
        int bt = g + 4*i;
        const uint4* rp = (const uint4*)(recpk + ((size_t)bt*1024 + n)*32);
        float o0 = bsp, o1 = 0.f;
        #pragma unroll
        for (int jj = 0; jj < 8; ++jj){
            uint4 rq = rp[jj];
            o0 = fdot2u(rq.x, wr[4*jj+0], o0);
            o1 = fdot2u(rq.y, wr[4*jj+1], o1);
            o0 = fdot2u(rq.z, wr[4*jj+2], o0);
            o1 = fdot2u(rq.w, wr[4*jj+3], o1);
        }
        size_t oidx = ((size_t)bt*1024 + n)*64 + l;
        float r = o0 + o1 + x[oidx];
        out[oidx] = lrelu_(r);
    }
}

extern "C" void kernel_launch(void* const* d_in, const int* in_sizes, int n_in,
                              void* d_out, int out_size, void* d_ws, size_t ws_size,
                              hipStream_t stream) {
    const float* x     = (const float*)d_in[0];
    const float* ne    = (const float*)d_in[1];
    const float* timeb = (const float*)d_in[2];
    const float* teb   = (const float*)d_in[3];
    const float* Wp    = (const float*)d_in[4];
    const float* bp    = (const float*)d_in[5];
    const float* tadj  = (const float*)d_in[6];
    const float* adj   = (const float*)d_in[7];
    const float* wspa  = (const float*)d_in[8];
    const float* bspa  = (const float*)d_in[9];

    float* out    = (float*)d_out;
    float* outc   = out  + (size_t)BT_*N_*64;      // c:   [BT,HS,N]
    float* outdyn = outc + (size_t)BT_*HS_*N_;     // dyn: [B,HT,TT]

    float* ws   = (float*)d_ws;
    float* sbuf = ws;                               // [BT,16,64]
    float* temb = sbuf + (size_t)BT_*HS_*64;        // [B,64,64]
    float* v2   = temb + (size_t)B_*HT_*64;         // [BT,16,64]
    unsigned int* recpk = (unsigned int*)(v2 + (size_t)BT_*HS_*64); // [BT,1024,32] u32

    (void)hipFuncSetAttribute((const void*)k_mega,
            hipFuncAttributeMaxDynamicSharedMemorySize, MEGA_LDS);

    k_mega<<<dim3(BT_), 512, MEGA_LDS, stream>>>(x, Wp, bp, teb, adj, outc, sbuf);
    k_dyn<<<dim3(B_, HT_), 192, 0, stream>>>(timeb, tadj, outdyn);
    k_tem<<<dim3(B_, 16), 256, 0, stream>>>(outdyn, sbuf, temb);
    k_retv2<<<dim3(B_, 48), 256, 0, stream>>>(outdyn, temb, sbuf, v2);
    k_rec<<<dim3(BT_, 8), 256, 0, stream>>>(outc, v2, recpk);
    k_final<<<dim3(N_), 256, 0, stream>>>(x, ne, wspa, bspa, recpk, out);
}

// Round 6
// 774.103 us; speedup vs baseline: 1.4632x; 1.2477x over previous
//
#include <hip/hip_runtime.h>
#include <math.h>

#define B_ 16
#define T_ 12
#define N_ 1024
#define D_ 64
#define HS_ 16
#define HT_ 64
#define TT_ 192
#define BT_ 192

typedef _Float16 f16x2 __attribute__((ext_vector_type(2)));

__device__ __forceinline__ unsigned int pkrtz(float a, float b){
    auto r = __builtin_amdgcn_cvt_pkrtz(a, b);
    return __builtin_bit_cast(unsigned int, r);
}
__device__ __forceinline__ float fdot2u(unsigned int a, unsigned int b, float c){
    return __builtin_amdgcn_fdot2(__builtin_bit_cast(f16x2, a),
                                  __builtin_bit_cast(f16x2, b), c, false);
}
__device__ __forceinline__ float loF(unsigned int a){ f16x2 h = __builtin_bit_cast(f16x2, a); return (float)h.x; }
__device__ __forceinline__ float hiF(unsigned int a){ f16x2 h = __builtin_bit_cast(f16x2, a); return (float)h.y; }

__device__ __forceinline__ float lrelu_(float v){ return v > 0.f ? v : 0.01f*v; }
__device__ __forceinline__ float squash_sc(float sn){ return (sn/(1.f+sn))/(sqrtf(sn)+1e-8f); }

__device__ __forceinline__ float wredsum64(float v){
    #pragma unroll
    for (int mk = 1; mk < 64; mk <<= 1) v += __shfl_xor(v, mk, 64);
    return v;
}

// PT layout: f16 pair (n=2m, n=2m+1) of P[.][d]; row d (stride 512 u32),
// XOR bank swizzle: quad mb at byte-column (4*mb) ^ ((d&7)<<2).
__device__ __forceinline__ int ptq_idx(int d, int mb){
    return d*512 + ((4*mb) ^ ((d & 7) << 2));
}

// dadj dot for one h (runtime h ok: no reg-array indexing inside)
__device__ __forceinline__ void adjdot(const float* __restrict__ adj,
        const float* tl, int h, int t, float& a0, float& a1){
    float s0 = 0.f, s1 = 0.f;
    #pragma unroll
    for (int e = 0; e < 16; ++e){
        float2 av = *(const float2*)(adj + (((e << 4) + h) << 10) + 2*t);
        s0 += tl[e]*av.x; s1 += tl[e]*av.y;
    }
    a0 = s0; a1 = s1;
}

#define MEGA_LDS 163840
// PT:  [0, 131072)            64 rows x 512 u32
// CL:  [131072, 163840)       u32[16][512]  (c as f16 n-pairs)
// TP:  [131072, 148480)       f32[64][68]   (overlaps CL; time-disjoint)
// VB:  [148480, 152832)       f32[16][68]   (overlaps CL; time-disjoint)
// XST: [131072, 139264)       u32[8][256]   (P-build only)

// Round-5 post-mortem: spills came from scheduler load-clustering in fully
// unrolled load loops (adj-logit sweep, bupd), not named-variable count.
// This version: no c[16] arrays (online softmax, recompute logits in phase B),
// sched_barrier(0) between h/dq iterations to bound instantaneous pressure.
__global__ __launch_bounds__(512, 1) void k_mega(
        const float* __restrict__ x, const float* __restrict__ Wp,
        const float* __restrict__ bp, const float* __restrict__ teb,
        const float* __restrict__ adj,
        float* __restrict__ cout, float* __restrict__ sbuf){
    extern __shared__ char smem[];
    unsigned int* PT  = (unsigned int*)smem;
    unsigned int* CL  = (unsigned int*)(smem + 131072);
    float*        TP  = (float*)(smem + 131072);
    unsigned int* XST = (unsigned int*)(smem + 131072);
    float*        VB  = (float*)(smem + 148480);

    const int t  = threadIdx.x;
    const int bt = blockIdx.x;
    const int w  = t >> 6, l = t & 63;
    const int o  = w & 1, G = w >> 1;   // h-oct, m-quarter for MAC

    // ---- P build: W rows (f16 packed) in regs; wave w -> rows [128w,128w+128)
    {
        unsigned int wpk[32];
        float bpd = bp[l];
        #pragma unroll
        for (int j = 0; j < 32; ++j){
            float2 w2 = *(const float2*)(Wp + l*64 + 2*j);
            wpk[j] = pkrtz(w2.x, w2.y);
        }
        unsigned int* xst = XST + w*256;
        const float* xb = x + (size_t)bt * 65536;
        int half = l >> 5, j32 = l & 31;
        for (int bi = 0; bi < 16; ++bi){
            int r0 = w*128 + bi*8;
            #pragma unroll
            for (int rr = 0; rr < 8; rr += 2){
                int row = r0 + rr + half;
                float2 xv = *(const float2*)(xb + row*64 + 2*j32);
                xst[(rr + half)*32 + j32] = pkrtz(xv.x, xv.y);
            }
            unsigned int pk4[4];
            #pragma unroll
            for (int pp = 0; pp < 4; ++pp){
                float ya0 = 0.f, ya1 = 0.f, yb0 = 0.f, yb1 = 0.f;
                #pragma unroll
                for (int jq = 0; jq < 8; ++jq){
                    uint4 xa  = *(uint4*)&xst[(2*pp)*32 + 4*jq];
                    uint4 xbq = *(uint4*)&xst[(2*pp+1)*32 + 4*jq];
                    ya0 = fdot2u(xa.x,  wpk[4*jq+0], ya0);
                    ya1 = fdot2u(xa.y,  wpk[4*jq+1], ya1);
                    ya0 = fdot2u(xa.z,  wpk[4*jq+2], ya0);
                    ya1 = fdot2u(xa.w,  wpk[4*jq+3], ya1);
                    yb0 = fdot2u(xbq.x, wpk[4*jq+0], yb0);
                    yb1 = fdot2u(xbq.y, wpk[4*jq+1], yb1);
                    yb0 = fdot2u(xbq.z, wpk[4*jq+2], yb0);
                    yb1 = fdot2u(xbq.w, wpk[4*jq+3], yb1);
                }
                float ya = bpd + ya0 + ya1;
                float yb = bpd + yb0 + yb1;
                float sna = wredsum64(ya*ya);
                float snb = wredsum64(yb*yb);
                pk4[pp] = pkrtz(ya*squash_sc(sna), yb*squash_sc(snb));
            }
            *(uint4*)&PT[ptq_idx(l, w*16 + bi)] = make_uint4(pk4[0], pk4[1], pk4[2], pk4[3]);
        }
    }

    float bb0[16], bb1[16];
    #pragma unroll
    for (int h = 0; h < 16; ++h){ bb0[h] = 0.f; bb1[h] = 0.f; }
    float v1a = 0.f, v1b = 0.f;

    #pragma unroll 1
    for (int pass = 0; pass < 5; ++pass){
        float tl[16];
        if (pass == 0 || pass == 4){
            #pragma unroll
            for (int e = 0; e < 16; ++e) tl[e] = teb[bt*16 + e];
        }

        // --- Phase A: online softmax stats (no c arrays; thread owns n0=2t,n1=2t+1)
        float M0 = -1e30f, S0 = 0.f, M1 = -1e30f, S1 = 0.f;
        #pragma unroll
        for (int h = 0; h < 16; ++h){
            float l0, l1;
            if (pass == 0 || pass == 4){
                adjdot(adj, tl, h, t, l0, l1);
                __builtin_amdgcn_sched_barrier(0);
                if (pass == 4){ l0 += bb0[h]; l1 += bb1[h]; }
            } else {
                l0 = bb0[h]; l1 = bb1[h];
            }
            float nM0 = fmaxf(M0, l0);
            S0 = S0*__expf(M0 - nM0) + __expf(l0 - nM0); M0 = nM0;
            float nM1 = fmaxf(M1, l1);
            S1 = S1*__expf(M1 - nM1) + __expf(l1 - nM1); M1 = nM1;
        }
        float i0 = 1.f/S0, i1 = 1.f/S1;

        // --- Phase B: recompute logits, write normalized c into CL
        __syncthreads();   // prev pass VB/CL readers done; P-build XST done (pass 0)
        #pragma unroll
        for (int h = 0; h < 16; ++h){
            float l0, l1;
            if (pass == 0 || pass == 4){
                adjdot(adj, tl, h, t, l0, l1);
                __builtin_amdgcn_sched_barrier(0);
                if (pass == 4){ l0 += bb0[h]; l1 += bb1[h]; }
            } else {
                l0 = bb0[h]; l1 = bb1[h];
            }
            float e0 = __expf(l0 - M0)*i0;
            float e1 = __expf(l1 - M1)*i1;
            CL[h*512 + t] = pkrtz(e0, e1);
            if (pass == 4){
                float2 cw; cw.x = e0; cw.y = e1;
                *(float2*)(cout + ((size_t)bt*16 + h)*1024 + 2*t) = cw;
            }
        }
        __syncthreads();

        // --- MAC: t[h][d] = sum_n c[h][n]*P[n][d]; wave (o,G): h-oct x m-quarter
        float acc[8];
        #pragma unroll
        for (int hh = 0; hh < 8; ++hh) acc[hh] = 0.f;
        #pragma unroll 2
        for (int q = 0; q < 32; ++q){
            int mb = G*32 + q;
            uint4 pt = *(uint4*)&PT[ptq_idx(l, mb)];
            #pragma unroll
            for (int hh = 0; hh < 8; ++hh){
                uint4 cq = *(uint4*)&CL[(8*o + hh)*512 + 4*mb];
                acc[hh] = fdot2u(cq.x, pt.x, acc[hh]);
                acc[hh] = fdot2u(cq.y, pt.y, acc[hh]);
                acc[hh] = fdot2u(cq.z, pt.z, acc[hh]);
                acc[hh] = fdot2u(cq.w, pt.w, acc[hh]);
            }
        }
        __syncthreads();               // all CL reads done (TP overlaps CL)
        #pragma unroll
        for (int hh = 0; hh < 8; ++hh) TP[(G*16 + 8*o + hh)*68 + l] = acc[hh];
        __syncthreads();

        // --- owner wave w reduces quarters for h = 2w, 2w+1 (lane = d)
        {
            float t0 = 0.f, t1 = 0.f;
            #pragma unroll
            for (int g2 = 0; g2 < 4; ++g2){
                t0 += TP[(g2*16 + 2*w    )*68 + l];
                t1 += TP[(g2*16 + 2*w + 1)*68 + l];
            }
            if (pass == 0){
                float sn0 = wredsum64(t0*t0), sn1 = wredsum64(t1*t1);
                v1a = t0*squash_sc(sn0); v1b = t1*squash_sc(sn1);
            } else if (pass < 4){
                float q0 = v1a*t0, q1 = v1b*t1;
                float sn0 = wredsum64(q0*q0), sn1 = wredsum64(q1*q1);
                VB[(2*w    )*68 + l] = q0*squash_sc(sn0);
                VB[(2*w + 1)*68 + l] = q1*squash_sc(sn1);
            } else {
                sbuf[((size_t)bt*16 + 2*w    )*64 + l] = t0;
                sbuf[((size_t)bt*16 + 2*w + 1)*64 + l] = t1;
            }
        }

        if (pass >= 1 && pass <= 3){
            __syncthreads();           // VB ready
            // bupd: thread owns pair m=t (n0=2t, n1=2t+1); dq serialized to
            // bound load clustering (round-5 spill source)
            int mb = t >> 2, off = t & 3;
            #pragma unroll 1
            for (int dq = 0; dq < 16; ++dq){
                float p0[4], p1[4];
                #pragma unroll
                for (int i = 0; i < 4; ++i){
                    unsigned int pv = PT[ptq_idx(dq*4 + i, mb) + off];
                    p0[i] = loF(pv); p1[i] = hiF(pv);
                }
                #pragma unroll
                for (int h = 0; h < 16; ++h){
                    float4 vb4 = *(float4*)&VB[h*68 + dq*4];
                    bb0[h] += vb4.x*p0[0] + vb4.y*p0[1] + vb4.z*p0[2] + vb4.w*p0[3];
                    bb1[h] += vb4.x*p1[0] + vb4.y*p1[1] + vb4.z*p1[2] + vb4.w*p1[3];
                }
                __builtin_amdgcn_sched_barrier(0);
            }
        }
    }
}

// dyn[b,h,k] = sum_e time_eb[b,e]*t_adj[e,h,k]
__global__ __launch_bounds__(192) void k_dyn(const float* __restrict__ timeb,
        const float* __restrict__ tadj, float* __restrict__ dyn){
    int b = blockIdx.x, h = blockIdx.y, k = threadIdx.x;
    float acc = 0.f;
    #pragma unroll
    for (int e = 0; e < 16; ++e)
        acc += timeb[b*16+e]*tadj[((size_t)e*HT_+h)*TT_ + k];
    dyn[((size_t)b*HT_+h)*TT_ + k] = acc;
}

// tem[b,h,d] = lrelu( sum_k dyn[b,h,k]*(s[b,k,d] + mask[k>>4]) )  grid (16,16) x 256
__global__ __launch_bounds__(256) void k_tem(const float* __restrict__ dyn,
        const float* __restrict__ sbuf, float* __restrict__ tem){
    int b = blockIdx.x, hg = blockIdx.y;
    int w = threadIdx.x >> 6, l = threadIdx.x & 63;
    int h = hg*4 + w;
    const float* dr = dyn + ((size_t)b*HT_ + h)*TT_;
    const float* sb = sbuf + (size_t)b*TT_*64;
    float a0 = 0.f, a1 = 0.f;
    #pragma unroll 4
    for (int k = 0; k < TT_; k += 2){
        float m0 = (float)((k>>4)+1) * (1.f/12.f);
        float m1 = (float)(((k+1)>>4)+1) * (1.f/12.f);
        a0 += dr[k]   * (sb[(size_t)k*64 + l]     + m0);
        a1 += dr[k+1] * (sb[(size_t)(k+1)*64 + l] + m1);
    }
    float a = a0 + a1;
    tem[((size_t)b*HT_ + h)*64 + l] = lrelu_(a);
}

// ret=lrelu(sum_h dyn*tem)+s; v2=squash(ret)   grid (16,48) x 256
__global__ __launch_bounds__(256) void k_retv2(const float* __restrict__ dyn,
        const float* __restrict__ temb, const float* __restrict__ sbuf,
        float* __restrict__ v2){
    int b = blockIdx.x, kg = blockIdx.y;
    int w = threadIdx.x >> 6, l = threadIdx.x & 63;
    int k = kg*4 + w;
    const float* tb = temb + (size_t)b*HT_*64;
    float a0 = 0.f, a1 = 0.f;
    #pragma unroll 4
    for (int h = 0; h < HT_; h += 2){
        a0 += dyn[((size_t)b*HT_ + h  )*TT_ + k] * tb[(size_t)h*64 + l];
        a1 += dyn[((size_t)b*HT_ + h+1)*TT_ + k] * tb[(size_t)(h+1)*64 + l];
    }
    float a = lrelu_(a0 + a1);
    float r = a + sbuf[((size_t)b*TT_ + k)*64 + l];
    float sn = wredsum64(r*r);
    v2[((size_t)b*TT_ + k)*64 + l] = r*squash_sc(sn);
}

// recon (f16 packed pairs): rec[bt,n,d] = sum_h c[bt,h,n]*v2[bt,h,d]  grid (192,8) x 256
__global__ __launch_bounds__(256) void k_rec(const float* __restrict__ cbuf,
        const float* __restrict__ v2, unsigned int* __restrict__ recpk){
    __shared__ float vL[16*68];
    __shared__ float cL[16*132];
    int bt = blockIdx.x, nc = blockIdx.y;
    int t = threadIdx.x, l = t & 63, g = t >> 6;
    #pragma unroll
    for (int i = 0; i < 4; ++i){
        int idx = i*256 + t;
        vL[(idx>>6)*68 + (idx&63)] = v2[(size_t)bt*1024 + idx];
    }
    #pragma unroll
    for (int i = 0; i < 8; ++i){
        int idx = i*256 + t;   // h = idx>>7, j = idx&127
        cL[(idx>>7)*132 + (idx&127)] =
            cbuf[((size_t)bt*16 + (idx>>7))*1024 + nc*128 + (idx&127)];
    }
    __syncthreads();
    float vreg[16];
    #pragma unroll
    for (int h = 0; h < 16; ++h) vreg[h] = vL[h*68 + l];
    #pragma unroll 4
    for (int i = 0; i < 32; ++i){
        int nl = g + 4*i;
        float a = 0.f;
        #pragma unroll
        for (int h = 0; h < 16; ++h) a += cL[h*132 + nl]*vreg[h];
        float ap = __shfl_xor(a, 1, 64);
        if (!(l & 1))
            recpk[((size_t)bt*1024 + nc*128 + nl)*32 + (l>>1)] = pkrtz(a, ap);
    }
}

// out = lrelu(rec @ wsp[n] + bsp[n] + x)   grid 1024 x 256
__global__ __launch_bounds__(256) void k_final(const float* __restrict__ x,
        const float* __restrict__ ne, const float* __restrict__ wspa,
        const float* __restrict__ bspa, const unsigned int* __restrict__ recpk,
        float* __restrict__ out){
    __shared__ float wspL[64*68];
    __shared__ float bspL[64];
    int n = blockIdx.x, t = threadIdx.x, l = t & 63, g = t >> 6;
    float nl16[16];
    #pragma unroll
    for (int e = 0; e < 16; ++e) nl16[e] = ne[n*16 + e];
    #pragma unroll
    for (int j = 0; j < 16; ++j){
        int io = j*256 + t;
        float a = 0.f;
        #pragma unroll
        for (int e = 0; e < 16; ++e) a += nl16[e]*wspa[(size_t)e*4096 + io];
        wspL[(io>>6)*68 + (io&63)] = a;
    }
    if (t < 64){
        float a = 0.f;
        #pragma unroll
        for (int e = 0; e < 16; ++e) a += nl16[e]*bspa[e*64 + t];
        bspL[t] = a;
    }
    __syncthreads();
    unsigned int wr[32];
    #pragma unroll
    for (int ip = 0; ip < 32; ++ip)
        wr[ip] = pkrtz(wspL[(2*ip)*68 + l], wspL[(2*ip+1)*68 + l]);
    float bsp = bspL[l];
    #pragma unroll 2
    for (int i = 0; i < 48; ++i){
        int bt = g + 4*i;
        const uint4* rp = (const uint4*)(recpk + ((size_t)bt*1024 + n)*32);
        float o0 = bsp, o1 = 0.f;
        #pragma unroll
        for (int jj = 0; jj < 8; ++jj){
            uint4 rq = rp[jj];
            o0 = fdot2u(rq.x, wr[4*jj+0], o0);
            o1 = fdot2u(rq.y, wr[4*jj+1], o1);
            o0 = fdot2u(rq.z, wr[4*jj+2], o0);
            o1 = fdot2u(rq.w, wr[4*jj+3], o1);
        }
        size_t oidx = ((size_t)bt*1024 + n)*64 + l;
        float r = o0 + o1 + x[oidx];
        out[oidx] = lrelu_(r);
    }
}

extern "C" void kernel_launch(void* const* d_in, const int* in_sizes, int n_in,
                              void* d_out, int out_size, void* d_ws, size_t ws_size,
                              hipStream_t stream) {
    const float* x     = (const float*)d_in[0];
    const float* ne    = (const float*)d_in[1];
    const float* timeb = (const float*)d_in[2];
    const float* teb   = (const float*)d_in[3];
    const float* Wp    = (const float*)d_in[4];
    const float* bp    = (const float*)d_in[5];
    const float* tadj  = (const float*)d_in[6];
    const float* adj   = (const float*)d_in[7];
    const float* wspa  = (const float*)d_in[8];
    const float* bspa  = (const float*)d_in[9];

    float* out    = (float*)d_out;
    float* outc   = out  + (size_t)BT_*N_*64;      // c:   [BT,HS,N]
    float* outdyn = outc + (size_t)BT_*HS_*N_;     // dyn: [B,HT,TT]

    float* ws   = (float*)d_ws;
    float* sbuf = ws;                               // [BT,16,64]
    float* temb = sbuf + (size_t)BT_*HS_*64;        // [B,64,64]
    float* v2   = temb + (size_t)B_*HT_*64;         // [BT,16,64]
    unsigned int* recpk = (unsigned int*)(v2 + (size_t)BT_*HS_*64); // [BT,1024,32] u32

    (void)hipFuncSetAttribute((const void*)k_mega,
            hipFuncAttributeMaxDynamicSharedMemorySize, MEGA_LDS);

    k_mega<<<dim3(BT_), 512, MEGA_LDS, stream>>>(x, Wp, bp, teb, adj, outc, sbuf);
    k_dyn<<<dim3(B_, HT_), 192, 0, stream>>>(timeb, tadj, outdyn);
    k_tem<<<dim3(B_, 16), 256, 0, stream>>>(outdyn, sbuf, temb);
    k_retv2<<<dim3(B_, 48), 256, 0, stream>>>(outdyn, temb, sbuf, v2);
    k_rec<<<dim3(BT_, 8), 256, 0, stream>>>(outc, v2, recpk);
    k_final<<<dim3(N_), 256, 0, stream>>>(x, ne, wspa, bspa, recpk, out);
}

// Round 7
// 300.742 us; speedup vs baseline: 3.7661x; 2.5740x over previous
//
#include <hip/hip_runtime.h>
#include <math.h>

#define B_ 16
#define T_ 12
#define N_ 1024
#define D_ 64
#define HS_ 16
#define HT_ 64
#define TT_ 192
#define BT_ 192

typedef _Float16 f16x2 __attribute__((ext_vector_type(2)));

__device__ __forceinline__ unsigned int pkrtz(float a, float b){
    auto r = __builtin_amdgcn_cvt_pkrtz(a, b);
    return __builtin_bit_cast(unsigned int, r);
}
__device__ __forceinline__ float fdot2u(unsigned int a, unsigned int b, float c){
    return __builtin_amdgcn_fdot2(__builtin_bit_cast(f16x2, a),
                                  __builtin_bit_cast(f16x2, b), c, false);
}
__device__ __forceinline__ float loF(unsigned int a){ f16x2 h = __builtin_bit_cast(f16x2, a); return (float)h.x; }
__device__ __forceinline__ float hiF(unsigned int a){ f16x2 h = __builtin_bit_cast(f16x2, a); return (float)h.y; }

__device__ __forceinline__ float lrelu_(float v){ return v > 0.f ? v : 0.01f*v; }
__device__ __forceinline__ float squash_sc(float sn){ return (sn/(1.f+sn))/(sqrtf(sn)+1e-8f); }

__device__ __forceinline__ float wredsum64(float v){
    #pragma unroll
    for (int mk = 1; mk < 64; mk <<= 1) v += __shfl_xor(v, mk, 64);
    return v;
}

// ---------------------------------------------------------------------------
// k_P: P = squash(x@W^T+b) -> f16 d-pairs  Ppk[bt][n][32]   grid (192,8) x 256
// ---------------------------------------------------------------------------
__global__ __launch_bounds__(256) void k_P(const float* __restrict__ x,
        const float* __restrict__ Wp, const float* __restrict__ bp,
        unsigned int* __restrict__ Ppk){
    __shared__ float xs[4][68];
    int bt = blockIdx.x, ch = blockIdx.y;
    int w = threadIdx.x >> 6, l = threadIdx.x & 63;
    float wr[64];
    #pragma unroll
    for (int k4 = 0; k4 < 16; ++k4){
        float4 t4 = *(const float4*)(Wp + l*64 + 4*k4);
        wr[4*k4+0]=t4.x; wr[4*k4+1]=t4.y; wr[4*k4+2]=t4.z; wr[4*k4+3]=t4.w;
    }
    float bpd = bp[l];
    const float* xb = x + ((size_t)bt*1024 + ch*128)*64;
    unsigned int* pb = Ppk + ((size_t)bt*1024 + ch*128)*32;
    for (int r = 0; r < 32; ++r){
        int row = r*4 + w;
        xs[w][l] = xb[row*64 + l];
        float y = bpd;
        #pragma unroll
        for (int k4 = 0; k4 < 16; ++k4){
            float4 xc = *(float4*)&xs[w][4*k4];
            y += xc.x*wr[4*k4] + xc.y*wr[4*k4+1] + xc.z*wr[4*k4+2] + xc.w*wr[4*k4+3];
        }
        float sn = wredsum64(y*y);
        float p = y*squash_sc(sn);
        float po = __shfl_xor(p, 1, 64);
        if (!(l & 1)) pb[row*32 + (l>>1)] = pkrtz(p, po);
    }
}

// ---------------------------------------------------------------------------
// kA: one routing sweep over an n-chunk of 128.  grid (192,8) x 256
// MODE 0: logits=dadj; write spart (chunk sum of P); no b I/O
// MODE 2: logits=v*P (b was 0); write bglob
// MODE 3: logits=bglob+v*P; write bglob
// MODE 4: logits=bglob+v*P+dadj; write cout (final c); no b write
// All modes: c=softmax_h(logits); partial t[h][d] -> tpart[bt][ch]
// ---------------------------------------------------------------------------
template<int MODE>
__global__ __launch_bounds__(256) void kA(const unsigned int* __restrict__ Ppk,
        const float* __restrict__ teb, const float* __restrict__ adj,
        const float* __restrict__ vbuf, float* __restrict__ bglob,
        float* __restrict__ tpart, float* __restrict__ spart,
        float* __restrict__ cout){
    __shared__ float PL[128][68];
    __shared__ float cL[128][20];
    __shared__ float bL[16][130];
    __shared__ float vL[16][68];
    int bt = blockIdx.x, ch = blockIdx.y;
    int t = threadIdx.x, w = t >> 6, l = t & 63;
    int n0 = ch*128;

    // stage P chunk (unpack f16 pairs -> f32)
    const uint4* Pg = (const uint4*)(Ppk + ((size_t)bt*1024 + n0)*32);
    #pragma unroll
    for (int k = 0; k < 4; ++k){
        int idx4 = t + 256*k;            // 0..1023
        uint4 u = Pg[idx4];
        int n = idx4 >> 3, jq = idx4 & 7;
        float* dst = &PL[n][jq*8];
        dst[0]=loF(u.x); dst[1]=hiF(u.x); dst[2]=loF(u.y); dst[3]=hiF(u.y);
        dst[4]=loF(u.z); dst[5]=hiF(u.z); dst[6]=loF(u.w); dst[7]=hiF(u.w);
    }
    if (MODE != 0){
        #pragma unroll
        for (int k = 0; k < 4; ++k){
            int idx = t + 256*k;
            vL[idx>>6][idx&63] = vbuf[(size_t)bt*1024 + idx];
        }
    }
    __syncthreads();

    if (MODE == 0 && t < 64){
        float s = 0.f;
        for (int n = 0; n < 128; ++n) s += PL[n][t];
        spart[((size_t)bt*8 + ch)*64 + t] = s;
    }

    // logits -> bL ; thread owns (n = t&127, h-group hg = t>>7 -> 8 h values)
    {
        int n = t & 127, hg = t >> 7;
        float acc8[8];
        #pragma unroll
        for (int i = 0; i < 8; ++i) acc8[i] = 0.f;
        if (MODE != 0){
            #pragma unroll 4
            for (int j = 0; j < 16; ++j){
                float4 p4 = *(float4*)&PL[n][4*j];
                #pragma unroll
                for (int i = 0; i < 8; ++i){
                    float4 v4 = *(float4*)&vL[hg*8+i][4*j];
                    acc8[i] += p4.x*v4.x + p4.y*v4.y + p4.z*v4.z + p4.w*v4.w;
                }
            }
            if (MODE == 3 || MODE == 4){
                #pragma unroll
                for (int i = 0; i < 8; ++i)
                    acc8[i] += bglob[((size_t)bt*16 + hg*8+i)*1024 + n0 + n];
            }
            if (MODE == 2 || MODE == 3){
                #pragma unroll
                for (int i = 0; i < 8; ++i)
                    bglob[((size_t)bt*16 + hg*8+i)*1024 + n0 + n] = acc8[i];
            }
        }
        if (MODE == 0 || MODE == 4){
            float tl[16];
            #pragma unroll
            for (int e = 0; e < 16; ++e) tl[e] = teb[bt*16 + e];
            #pragma unroll
            for (int i = 0; i < 8; ++i){
                int h = hg*8 + i;
                float s = 0.f;
                #pragma unroll
                for (int e = 0; e < 16; ++e)
                    s += tl[e]*adj[(((e<<4) + h)<<10) + n0 + n];
                acc8[i] += s;
            }
        }
        #pragma unroll
        for (int i = 0; i < 8; ++i) bL[hg*8+i][n] = acc8[i];
    }
    __syncthreads();

    // softmax over h per n
    if (t < 128){
        int n = t;
        float M = -1e30f;
        #pragma unroll
        for (int h = 0; h < 16; ++h) M = fmaxf(M, bL[h][n]);
        float S = 0.f; float ev[16];
        #pragma unroll
        for (int h = 0; h < 16; ++h){ ev[h] = __expf(bL[h][n] - M); S += ev[h]; }
        float inv = 1.f/S;
        #pragma unroll
        for (int h = 0; h < 16; ++h){
            float cv = ev[h]*inv;
            cL[n][h] = cv;
            if (MODE == 4) cout[((size_t)bt*16 + h)*1024 + n0 + n] = cv;
        }
    }
    __syncthreads();

    // partial t[h][d]: wave w -> h 4w..4w+3, lane = d
    float acc[4] = {0.f,0.f,0.f,0.f};
    #pragma unroll 4
    for (int n = 0; n < 128; ++n){
        float4 c4 = *(float4*)&cL[n][4*w];
        float p = PL[n][l];
        acc[0] += c4.x*p; acc[1] += c4.y*p; acc[2] += c4.z*p; acc[3] += c4.w*p;
    }
    #pragma unroll
    for (int i = 0; i < 4; ++i)
        tpart[(((size_t)bt*8 + ch)*16 + 4*w + i)*64 + l] = acc[i];
}

// ---------------------------------------------------------------------------
// kB: reduce partials, squash.  grid 192 x 256
// MODE 0: v1=squash(t); vout=squash(v1*sumP/16)  (pass 0 + folded pass 1)
// MODE 1: vout=squash(v1*t)
// MODE 2: vout=t (raw s)
// ---------------------------------------------------------------------------
template<int MODE>
__global__ __launch_bounds__(256) void kB(const float* __restrict__ tpart,
        const float* __restrict__ spart, const float* __restrict__ v1buf,
        float* __restrict__ v1out, float* __restrict__ vout){
    int bt = blockIdx.x;
    int w = threadIdx.x >> 6, l = threadIdx.x & 63;
    float sp = 0.f;
    if (MODE == 0){
        #pragma unroll
        for (int c = 0; c < 8; ++c) sp += spart[((size_t)bt*8 + c)*64 + l];
        sp *= (1.f/16.f);
    }
    #pragma unroll
    for (int i = 0; i < 4; ++i){
        int h = 4*w + i;
        float s = 0.f;
        #pragma unroll
        for (int c = 0; c < 8; ++c)
            s += tpart[(((size_t)bt*8 + c)*16 + h)*64 + l];
        if (MODE == 2){
            vout[((size_t)bt*16 + h)*64 + l] = s;
        } else if (MODE == 0){
            float sn = wredsum64(s*s);
            float v1 = s*squash_sc(sn);
            v1out[((size_t)bt*16 + h)*64 + l] = v1;
            float q = v1*sp;
            float sn2 = wredsum64(q*q);
            vout[((size_t)bt*16 + h)*64 + l] = q*squash_sc(sn2);
        } else {
            float q = v1buf[((size_t)bt*16 + h)*64 + l]*s;
            float sn = wredsum64(q*q);
            vout[((size_t)bt*16 + h)*64 + l] = q*squash_sc(sn);
        }
    }
}

// dyn[b,h,k] = sum_e time_eb[b,e]*t_adj[e,h,k]
__global__ __launch_bounds__(192) void k_dyn(const float* __restrict__ timeb,
        const float* __restrict__ tadj, float* __restrict__ dyn){
    int b = blockIdx.x, h = blockIdx.y, k = threadIdx.x;
    float acc = 0.f;
    #pragma unroll
    for (int e = 0; e < 16; ++e)
        acc += timeb[b*16+e]*tadj[((size_t)e*HT_+h)*TT_ + k];
    dyn[((size_t)b*HT_+h)*TT_ + k] = acc;
}

// tem[b,h,d] = lrelu( sum_k dyn[b,h,k]*(s[b,k,d] + mask[k>>4]) )  grid (16,16) x 256
__global__ __launch_bounds__(256) void k_tem(const float* __restrict__ dyn,
        const float* __restrict__ sbuf, float* __restrict__ tem){
    int b = blockIdx.x, hg = blockIdx.y;
    int w = threadIdx.x >> 6, l = threadIdx.x & 63;
    int h = hg*4 + w;
    const float* dr = dyn + ((size_t)b*HT_ + h)*TT_;
    const float* sb = sbuf + (size_t)b*TT_*64;
    float a0 = 0.f, a1 = 0.f;
    #pragma unroll 4
    for (int k = 0; k < TT_; k += 2){
        float m0 = (float)((k>>4)+1) * (1.f/12.f);
        float m1 = (float)(((k+1)>>4)+1) * (1.f/12.f);
        a0 += dr[k]   * (sb[(size_t)k*64 + l]     + m0);
        a1 += dr[k+1] * (sb[(size_t)(k+1)*64 + l] + m1);
    }
    tem[((size_t)b*HT_ + h)*64 + l] = lrelu_(a0 + a1);
}

// ret=lrelu(sum_h dyn*tem)+s; v2=squash(ret)   grid (16,48) x 256
__global__ __launch_bounds__(256) void k_retv2(const float* __restrict__ dyn,
        const float* __restrict__ temb, const float* __restrict__ sbuf,
        float* __restrict__ v2){
    int b = blockIdx.x, kg = blockIdx.y;
    int w = threadIdx.x >> 6, l = threadIdx.x & 63;
    int k = kg*4 + w;
    const float* tb = temb + (size_t)b*HT_*64;
    float a0 = 0.f, a1 = 0.f;
    #pragma unroll 4
    for (int h = 0; h < HT_; h += 2){
        a0 += dyn[((size_t)b*HT_ + h  )*TT_ + k] * tb[(size_t)h*64 + l];
        a1 += dyn[((size_t)b*HT_ + h+1)*TT_ + k] * tb[(size_t)(h+1)*64 + l];
    }
    float a = lrelu_(a0 + a1);
    float r = a + sbuf[((size_t)b*TT_ + k)*64 + l];
    float sn = wredsum64(r*r);
    v2[((size_t)b*TT_ + k)*64 + l] = r*squash_sc(sn);
}

// recon (f16 packed pairs): rec[bt,n,d] = sum_h c[bt,h,n]*v2[bt,h,d]  grid (192,8) x 256
__global__ __launch_bounds__(256) void k_rec(const float* __restrict__ cbuf,
        const float* __restrict__ v2, unsigned int* __restrict__ recpk){
    __shared__ float vL[16*68];
    __shared__ float cL[16*132];
    int bt = blockIdx.x, nc = blockIdx.y;
    int t = threadIdx.x, l = t & 63, g = t >> 6;
    #pragma unroll
    for (int i = 0; i < 4; ++i){
        int idx = i*256 + t;
        vL[(idx>>6)*68 + (idx&63)] = v2[(size_t)bt*1024 + idx];
    }
    #pragma unroll
    for (int i = 0; i < 8; ++i){
        int idx = i*256 + t;
        cL[(idx>>7)*132 + (idx&127)] =
            cbuf[((size_t)bt*16 + (idx>>7))*1024 + nc*128 + (idx&127)];
    }
    __syncthreads();
    float vreg[16];
    #pragma unroll
    for (int h = 0; h < 16; ++h) vreg[h] = vL[h*68 + l];
    #pragma unroll 4
    for (int i = 0; i < 32; ++i){
        int nl = g + 4*i;
        float a = 0.f;
        #pragma unroll
        for (int h = 0; h < 16; ++h) a += cL[h*132 + nl]*vreg[h];
        float ap = __shfl_xor(a, 1, 64);
        if (!(l & 1))
            recpk[((size_t)bt*1024 + nc*128 + nl)*32 + (l>>1)] = pkrtz(a, ap);
    }
}

// out = lrelu(rec @ wsp[n] + bsp[n] + x)   grid 1024 x 256
__global__ __launch_bounds__(256) void k_final(const float* __restrict__ x,
        const float* __restrict__ ne, const float* __restrict__ wspa,
        const float* __restrict__ bspa, const unsigned int* __restrict__ recpk,
        float* __restrict__ out){
    __shared__ float wspL[64*68];
    __shared__ float bspL[64];
    int n = blockIdx.x, t = threadIdx.x, l = t & 63, g = t >> 6;
    float nl16[16];
    #pragma unroll
    for (int e = 0; e < 16; ++e) nl16[e] = ne[n*16 + e];
    #pragma unroll
    for (int j = 0; j < 16; ++j){
        int io = j*256 + t;
        float a = 0.f;
        #pragma unroll
        for (int e = 0; e < 16; ++e) a += nl16[e]*wspa[(size_t)e*4096 + io];
        wspL[(io>>6)*68 + (io&63)] = a;
    }
    if (t < 64){
        float a = 0.f;
        #pragma unroll
        for (int e = 0; e < 16; ++e) a += nl16[e]*bspa[e*64 + t];
        bspL[t] = a;
    }
    __syncthreads();
    unsigned int wr[32];
    #pragma unroll
    for (int ip = 0; ip < 32; ++ip)
        wr[ip] = pkrtz(wspL[(2*ip)*68 + l], wspL[(2*ip+1)*68 + l]);
    float bsp = bspL[l];
    #pragma unroll 2
    for (int i = 0; i < 48; ++i){
        int bt = g + 4*i;
        const uint4* rp = (const uint4*)(recpk + ((size_t)bt*1024 + n)*32);
        float o0 = bsp, o1 = 0.f;
        #pragma unroll
        for (int jj = 0; jj < 8; ++jj){
            uint4 rq = rp[jj];
            o0 = fdot2u(rq.x, wr[4*jj+0], o0);
            o1 = fdot2u(rq.y, wr[4*jj+1], o1);
            o0 = fdot2u(rq.z, wr[4*jj+2], o0);
            o1 = fdot2u(rq.w, wr[4*jj+3], o1);
        }
        size_t oidx = ((size_t)bt*1024 + n)*64 + l;
        out[oidx] = lrelu_(o0 + o1 + x[oidx]);
    }
}

extern "C" void kernel_launch(void* const* d_in, const int* in_sizes, int n_in,
                              void* d_out, int out_size, void* d_ws, size_t ws_size,
                              hipStream_t stream) {
    const float* x     = (const float*)d_in[0];
    const float* ne    = (const float*)d_in[1];
    const float* timeb = (const float*)d_in[2];
    const float* teb   = (const float*)d_in[3];
    const float* Wp    = (const float*)d_in[4];
    const float* bp    = (const float*)d_in[5];
    const float* tadj  = (const float*)d_in[6];
    const float* adj   = (const float*)d_in[7];
    const float* wspa  = (const float*)d_in[8];
    const float* bspa  = (const float*)d_in[9];

    float* out    = (float*)d_out;
    float* outc   = out  + (size_t)BT_*N_*64;      // c:   [BT,HS,N]
    float* outdyn = outc + (size_t)BT_*HS_*N_;     // dyn: [B,HT,TT]

    char* ws = (char*)d_ws;
    unsigned int* Ppk   = (unsigned int*)ws;                        // 25.2 MB
    float* bglob = (float*)(ws + 25165824);                         // 12.6 MB
    float* tpart = bglob + (size_t)BT_*HS_*N_;                      // 6.3 MB
    float* spart = tpart + (size_t)BT_*8*HS_*64;                    // 0.39 MB
    float* vbuf  = spart + (size_t)BT_*8*64;                        // 0.79 MB
    float* v1buf = vbuf  + (size_t)BT_*HS_*64;
    float* sbuf  = v1buf + (size_t)BT_*HS_*64;
    float* temb  = sbuf  + (size_t)BT_*HS_*64;
    float* v2    = temb  + (size_t)B_*HT_*64;
    unsigned int* recpk = (unsigned int*)(v2 + (size_t)BT_*HS_*64); // 25.2 MB

    k_P<<<dim3(BT_, 8), 256, 0, stream>>>(x, Wp, bp, Ppk);

    // pass 0 (test1 -> v1) + folded pass 1 (uniform c -> v_r1)
    kA<0><<<dim3(BT_, 8), 256, 0, stream>>>(Ppk, teb, adj, nullptr, nullptr, tpart, spart, nullptr);
    kB<0><<<dim3(BT_), 256, 0, stream>>>(tpart, spart, nullptr, v1buf, vbuf);

    // pass 2: b2 = v_r1*P; c2; t2 -> v_r2
    kA<2><<<dim3(BT_, 8), 256, 0, stream>>>(Ppk, teb, adj, vbuf, bglob, tpart, nullptr, nullptr);
    kB<1><<<dim3(BT_), 256, 0, stream>>>(tpart, nullptr, v1buf, nullptr, vbuf);

    // pass 3: b3 = b2 + v_r2*P; c3; t3 -> v_r3
    kA<3><<<dim3(BT_, 8), 256, 0, stream>>>(Ppk, teb, adj, vbuf, bglob, tpart, nullptr, nullptr);
    kB<1><<<dim3(BT_), 256, 0, stream>>>(tpart, nullptr, v1buf, nullptr, vbuf);

    // pass 4: c_final = softmax(b3 + v_r3*P + dadj); s
    kA<4><<<dim3(BT_, 8), 256, 0, stream>>>(Ppk, teb, adj, vbuf, bglob, tpart, nullptr, outc);
    kB<2><<<dim3(BT_), 256, 0, stream>>>(tpart, nullptr, nullptr, nullptr, sbuf);

    k_dyn<<<dim3(B_, HT_), 192, 0, stream>>>(timeb, tadj, outdyn);
    k_tem<<<dim3(B_, 16), 256, 0, stream>>>(outdyn, sbuf, temb);
    k_retv2<<<dim3(B_, 48), 256, 0, stream>>>(outdyn, temb, sbuf, v2);
    k_rec<<<dim3(BT_, 8), 256, 0, stream>>>(outc, v2, recpk);
    k_final<<<dim3(N_), 256, 0, stream>>>(x, ne, wspa, bspa, recpk, out);
}

// Round 8
// 237.071 us; speedup vs baseline: 4.7776x; 1.2686x over previous
//
#include <hip/hip_runtime.h>
#include <math.h>

#define B_ 16
#define T_ 12
#define N_ 1024
#define D_ 64
#define HS_ 16
#define HT_ 64
#define TT_ 192
#define BT_ 192

typedef _Float16 f16x2 __attribute__((ext_vector_type(2)));

__device__ __forceinline__ unsigned int pkrtz(float a, float b){
    auto r = __builtin_amdgcn_cvt_pkrtz(a, b);
    return __builtin_bit_cast(unsigned int, r);
}
__device__ __forceinline__ float fdot2u(unsigned int a, unsigned int b, float c){
    return __builtin_amdgcn_fdot2(__builtin_bit_cast(f16x2, a),
                                  __builtin_bit_cast(f16x2, b), c, false);
}
__device__ __forceinline__ float loF(unsigned int a){ f16x2 h = __builtin_bit_cast(f16x2, a); return (float)h.x; }
__device__ __forceinline__ float hiF(unsigned int a){ f16x2 h = __builtin_bit_cast(f16x2, a); return (float)h.y; }

__device__ __forceinline__ float lrelu_(float v){ return v > 0.f ? v : 0.01f*v; }
__device__ __forceinline__ float squash_sc(float sn){ return (sn/(1.f+sn))/(sqrtf(sn)+1e-8f); }

__device__ __forceinline__ float wredsum64(float v){
    #pragma unroll
    for (int mk = 1; mk < 64; mk <<= 1) v += __shfl_xor(v, mk, 64);
    return v;
}

// ---------------------------------------------------------------------------
// k_P: P = squash(x@W^T+b) -> f16 d-pairs  Ppk[bt][n][32]   grid (192,8) x 256
// W packed f16 (32 VGPR) + (256,1) bounds: round-7 showed VGPR=48 heuristic
// forced W rematerialization from memory every row (100us kernel).
// ---------------------------------------------------------------------------
__global__ __launch_bounds__(256, 1) void k_P(const float* __restrict__ x,
        const float* __restrict__ Wp, const float* __restrict__ bp,
        unsigned int* __restrict__ Ppk){
    __shared__ unsigned int xst[4][256];   // per-wave: 8 rows x 32 d-pairs
    int w = threadIdx.x >> 6, l = threadIdx.x & 63;
    unsigned int wpk[32];
    #pragma unroll
    for (int j = 0; j < 32; ++j){
        float2 w2 = *(const float2*)(Wp + l*64 + 2*j);
        wpk[j] = pkrtz(w2.x, w2.y);
    }
    float bpd = bp[l];
    size_t rbase = ((size_t)blockIdx.x*1024 + blockIdx.y*128 + w*32);
    const float* xb = x + rbase*64;
    unsigned int* pb = Ppk + rbase*32;
    int half = l >> 5, j32 = l & 31;
    for (int bi = 0; bi < 4; ++bi){
        #pragma unroll
        for (int rr = 0; rr < 8; rr += 2){
            int row = bi*8 + rr + half;
            float2 xv = *(const float2*)(xb + row*64 + 2*j32);
            xst[w][(rr + half)*32 + j32] = pkrtz(xv.x, xv.y);
        }
        #pragma unroll
        for (int r = 0; r < 8; ++r){
            float y0 = 0.f, y1 = 0.f;
            #pragma unroll
            for (int jq = 0; jq < 8; ++jq){
                uint4 xa = *(uint4*)&xst[w][r*32 + 4*jq];
                y0 = fdot2u(xa.x, wpk[4*jq+0], y0);
                y1 = fdot2u(xa.y, wpk[4*jq+1], y1);
                y0 = fdot2u(xa.z, wpk[4*jq+2], y0);
                y1 = fdot2u(xa.w, wpk[4*jq+3], y1);
            }
            float y = bpd + y0 + y1;
            float sn = wredsum64(y*y);
            float p = y*squash_sc(sn);
            float po = __shfl_xor(p, 1, 64);
            if (!(l & 1)) pb[(bi*8 + r)*32 + (l>>1)] = pkrtz(p, po);
        }
    }
}

// ---------------------------------------------------------------------------
// k_dadj: dadj[bt,h,n] = sum_e teb[bt,e]*adj[e,h,n]   grid (192,16) x 256
// ---------------------------------------------------------------------------
__global__ __launch_bounds__(256) void k_dadj(const float* __restrict__ teb,
        const float* __restrict__ adj, float* __restrict__ dadj){
    int bt = blockIdx.x, h = blockIdx.y, n4 = threadIdx.x;
    float tl[16];
    #pragma unroll
    for (int e = 0; e < 16; ++e) tl[e] = teb[bt*16 + e];
    float4 acc = {0.f,0.f,0.f,0.f};
    #pragma unroll
    for (int e = 0; e < 16; ++e){
        float4 a = ((const float4*)(adj + ((size_t)(e*16 + h) << 10)))[n4];
        acc.x += tl[e]*a.x; acc.y += tl[e]*a.y; acc.z += tl[e]*a.z; acc.w += tl[e]*a.w;
    }
    ((float4*)(dadj + ((size_t)bt*16 + h)*1024))[n4] = acc;
}

// ---------------------------------------------------------------------------
// kA: one routing sweep over an n-chunk of 128.  grid (192,8) x 256
// Logits (b = vsum.P since k_test=P): MODE 0: dadj only (+spart);
// MODE 1: vsum.P; MODE 2: vsum.P + dadj, write cout.
// Then c=softmax_h, partial t[h][d] -> tpart[bt][ch].
// ---------------------------------------------------------------------------
template<int MODE>
__global__ __launch_bounds__(256, 2) void kA(const unsigned int* __restrict__ Ppk,
        const float* __restrict__ dadj, const float* __restrict__ vsum,
        float* __restrict__ tpart, float* __restrict__ spart,
        float* __restrict__ cout){
    __shared__ unsigned int PL[128*36];   // f16 pairs, stride 36 (b128-aligned)
    __shared__ unsigned int vLp[16*36];
    __shared__ float bL[16*130];
    __shared__ float cL[128*20];
    int bt = blockIdx.x, ch = blockIdx.y;
    int t = threadIdx.x, w = t >> 6, l = t & 63;
    int n0 = ch*128;

    const uint4* Pg = (const uint4*)(Ppk + ((size_t)bt*1024 + n0)*32);
    #pragma unroll
    for (int k = 0; k < 4; ++k){
        int idx4 = t + 256*k;
        uint4 u = Pg[idx4];
        *(uint4*)&PL[(idx4 >> 3)*36 + 4*(idx4 & 7)] = u;
    }
    if (MODE != 0){
        #pragma unroll
        for (int k = 0; k < 2; ++k){
            int idx = t + 256*k;   // h = idx>>5, j = idx&31
            float2 v2 = *(const float2*)(vsum + (size_t)bt*1024 + 2*idx);
            vLp[(idx >> 5)*36 + (idx & 31)] = pkrtz(v2.x, v2.y);
        }
    }
    __syncthreads();

    // logits -> bL ; thread owns (n = t&127, hg = t>>7 covering 8 h)
    {
        int n = t & 127, hg = t >> 7;
        float acc8[8];
        #pragma unroll
        for (int i = 0; i < 8; ++i) acc8[i] = 0.f;
        if (MODE != 0){
            #pragma unroll
            for (int j = 0; j < 8; ++j){
                uint4 pq = *(uint4*)&PL[n*36 + 4*j];
                #pragma unroll
                for (int i = 0; i < 8; ++i){
                    uint4 vq = *(uint4*)&vLp[(hg*8 + i)*36 + 4*j];
                    acc8[i] = fdot2u(pq.x, vq.x, acc8[i]);
                    acc8[i] = fdot2u(pq.y, vq.y, acc8[i]);
                    acc8[i] = fdot2u(pq.z, vq.z, acc8[i]);
                    acc8[i] = fdot2u(pq.w, vq.w, acc8[i]);
                }
            }
        }
        if (MODE != 1){
            #pragma unroll
            for (int i = 0; i < 8; ++i)
                acc8[i] += dadj[((size_t)bt*16 + hg*8 + i)*1024 + n0 + n];
        }
        #pragma unroll
        for (int i = 0; i < 8; ++i) bL[(hg*8 + i)*130 + n] = acc8[i];
    }
    __syncthreads();

    // softmax over h per n
    if (t < 128){
        int n = t;
        float M = -1e30f;
        #pragma unroll
        for (int h = 0; h < 16; ++h) M = fmaxf(M, bL[h*130 + n]);
        float S = 0.f; float ev[16];
        #pragma unroll
        for (int h = 0; h < 16; ++h){ ev[h] = __expf(bL[h*130 + n] - M); S += ev[h]; }
        float inv = 1.f/S;
        #pragma unroll
        for (int h = 0; h < 16; ++h){
            float cv = ev[h]*inv;
            cL[n*20 + h] = cv;
            if (MODE == 2) cout[((size_t)bt*16 + h)*1024 + n0 + n] = cv;
        }
    }
    __syncthreads();

    // partial t[h][d]: wave w -> h 4w..4w+3, lane = d; sumP folded in (MODE 0)
    float acc[4] = {0.f,0.f,0.f,0.f};
    float sp = 0.f;
    #pragma unroll 2
    for (int n = 0; n < 128; ++n){
        unsigned int pv = PL[n*36 + (l >> 1)];
        float p = (l & 1) ? hiF(pv) : loF(pv);
        float4 c4 = *(float4*)&cL[n*20 + 4*w];
        acc[0] += c4.x*p; acc[1] += c4.y*p; acc[2] += c4.z*p; acc[3] += c4.w*p;
        if (MODE == 0) sp += p;
    }
    #pragma unroll
    for (int i = 0; i < 4; ++i)
        tpart[(((size_t)bt*8 + ch)*16 + 4*w + i)*64 + l] = acc[i];
    if (MODE == 0 && w == 0)
        spart[((size_t)bt*8 + ch)*64 + l] = sp;
}

// ---------------------------------------------------------------------------
// kB: reduce partials, squash.  grid 192 x 256
// MODE 0: v1=squash(t); v_r1=squash(v1*sumP/16); vsum=v_r1
// MODE 1: v=squash(v1*t); vsum+=v
// MODE 2: s=t raw
// ---------------------------------------------------------------------------
template<int MODE>
__global__ __launch_bounds__(256) void kB(const float* __restrict__ tpart,
        const float* __restrict__ spart, float* __restrict__ v1io,
        float* __restrict__ vsum, float* __restrict__ sout){
    int bt = blockIdx.x;
    int w = threadIdx.x >> 6, l = threadIdx.x & 63;
    float sp = 0.f;
    if (MODE == 0){
        #pragma unroll
        for (int c = 0; c < 8; ++c) sp += spart[((size_t)bt*8 + c)*64 + l];
        sp *= (1.f/16.f);
    }
    #pragma unroll
    for (int i = 0; i < 4; ++i){
        int h = 4*w + i;
        float s = 0.f;
        #pragma unroll
        for (int c = 0; c < 8; ++c)
            s += tpart[(((size_t)bt*8 + c)*16 + h)*64 + l];
        size_t oi = ((size_t)bt*16 + h)*64 + l;
        if (MODE == 2){
            sout[oi] = s;
        } else if (MODE == 0){
            float sn = wredsum64(s*s);
            float v1 = s*squash_sc(sn);
            v1io[oi] = v1;
            float q = v1*sp;
            float sn2 = wredsum64(q*q);
            vsum[oi] = q*squash_sc(sn2);
        } else {
            float q = v1io[oi]*s;
            float sn = wredsum64(q*q);
            vsum[oi] += q*squash_sc(sn);
        }
    }
}

// dyn[b,h,k] = sum_e time_eb[b,e]*t_adj[e,h,k]
__global__ __launch_bounds__(192) void k_dyn(const float* __restrict__ timeb,
        const float* __restrict__ tadj, float* __restrict__ dyn){
    int b = blockIdx.x, h = blockIdx.y, k = threadIdx.x;
    float acc = 0.f;
    #pragma unroll
    for (int e = 0; e < 16; ++e)
        acc += timeb[b*16+e]*tadj[((size_t)e*HT_+h)*TT_ + k];
    dyn[((size_t)b*HT_+h)*TT_ + k] = acc;
}

// tem[b,h,d] = lrelu( sum_k dyn[b,h,k]*(s[b,k,d] + mask[k>>4]) )  grid (16,16) x 256
__global__ __launch_bounds__(256) void k_tem(const float* __restrict__ dyn,
        const float* __restrict__ sbuf, float* __restrict__ tem){
    int b = blockIdx.x, hg = blockIdx.y;
    int w = threadIdx.x >> 6, l = threadIdx.x & 63;
    int h = hg*4 + w;
    const float* dr = dyn + ((size_t)b*HT_ + h)*TT_;
    const float* sb = sbuf + (size_t)b*TT_*64;
    float a0 = 0.f, a1 = 0.f;
    #pragma unroll 4
    for (int k = 0; k < TT_; k += 2){
        float m0 = (float)((k>>4)+1) * (1.f/12.f);
        float m1 = (float)(((k+1)>>4)+1) * (1.f/12.f);
        a0 += dr[k]   * (sb[(size_t)k*64 + l]     + m0);
        a1 += dr[k+1] * (sb[(size_t)(k+1)*64 + l] + m1);
    }
    tem[((size_t)b*HT_ + h)*64 + l] = lrelu_(a0 + a1);
}

// ret=lrelu(sum_h dyn*tem)+s; v2=squash(ret)   grid (16,48) x 256
__global__ __launch_bounds__(256) void k_retv2(const float* __restrict__ dyn,
        const float* __restrict__ temb, const float* __restrict__ sbuf,
        float* __restrict__ v2){
    int b = blockIdx.x, kg = blockIdx.y;
    int w = threadIdx.x >> 6, l = threadIdx.x & 63;
    int k = kg*4 + w;
    const float* tb = temb + (size_t)b*HT_*64;
    float a0 = 0.f, a1 = 0.f;
    #pragma unroll 4
    for (int h = 0; h < HT_; h += 2){
        a0 += dyn[((size_t)b*HT_ + h  )*TT_ + k] * tb[(size_t)h*64 + l];
        a1 += dyn[((size_t)b*HT_ + h+1)*TT_ + k] * tb[(size_t)(h+1)*64 + l];
    }
    float a = lrelu_(a0 + a1);
    float r = a + sbuf[((size_t)b*TT_ + k)*64 + l];
    float sn = wredsum64(r*r);
    v2[((size_t)b*TT_ + k)*64 + l] = r*squash_sc(sn);
}

// recon (f16 packed pairs): rec[bt,n,d] = sum_h c[bt,h,n]*v2[bt,h,d]  grid (192,8) x 256
__global__ __launch_bounds__(256) void k_rec(const float* __restrict__ cbuf,
        const float* __restrict__ v2, unsigned int* __restrict__ recpk){
    __shared__ float vL[16*68];
    __shared__ float cL[16*132];
    int bt = blockIdx.x, nc = blockIdx.y;
    int t = threadIdx.x, l = t & 63, g = t >> 6;
    #pragma unroll
    for (int i = 0; i < 4; ++i){
        int idx = i*256 + t;
        vL[(idx>>6)*68 + (idx&63)] = v2[(size_t)bt*1024 + idx];
    }
    #pragma unroll
    for (int i = 0; i < 8; ++i){
        int idx = i*256 + t;
        cL[(idx>>7)*132 + (idx&127)] =
            cbuf[((size_t)bt*16 + (idx>>7))*1024 + nc*128 + (idx&127)];
    }
    __syncthreads();
    float vreg[16];
    #pragma unroll
    for (int h = 0; h < 16; ++h) vreg[h] = vL[h*68 + l];
    #pragma unroll 4
    for (int i = 0; i < 32; ++i){
        int nl = g + 4*i;
        float a = 0.f;
        #pragma unroll
        for (int h = 0; h < 16; ++h) a += cL[h*132 + nl]*vreg[h];
        float ap = __shfl_xor(a, 1, 64);
        if (!(l & 1))
            recpk[((size_t)bt*1024 + nc*128 + nl)*32 + (l>>1)] = pkrtz(a, ap);
    }
}

// out = lrelu(rec @ wsp[n] + bsp[n] + x)   grid 1024 x 256
__global__ __launch_bounds__(256) void k_final(const float* __restrict__ x,
        const float* __restrict__ ne, const float* __restrict__ wspa,
        const float* __restrict__ bspa, const unsigned int* __restrict__ recpk,
        float* __restrict__ out){
    __shared__ float wspL[64*68];
    __shared__ float bspL[64];
    int n = blockIdx.x, t = threadIdx.x, l = t & 63, g = t >> 6;
    float nl16[16];
    #pragma unroll
    for (int e = 0; e < 16; ++e) nl16[e] = ne[n*16 + e];
    #pragma unroll
    for (int j = 0; j < 16; ++j){
        int io = j*256 + t;
        float a = 0.f;
        #pragma unroll
        for (int e = 0; e < 16; ++e) a += nl16[e]*wspa[(size_t)e*4096 + io];
        wspL[(io>>6)*68 + (io&63)] = a;
    }
    if (t < 64){
        float a = 0.f;
        #pragma unroll
        for (int e = 0; e < 16; ++e) a += nl16[e]*bspa[e*64 + t];
        bspL[t] = a;
    }
    __syncthreads();
    unsigned int wr[32];
    #pragma unroll
    for (int ip = 0; ip < 32; ++ip)
        wr[ip] = pkrtz(wspL[(2*ip)*68 + l], wspL[(2*ip+1)*68 + l]);
    float bsp = bspL[l];
    #pragma unroll 2
    for (int i = 0; i < 48; ++i){
        int bt = g + 4*i;
        const uint4* rp = (const uint4*)(recpk + ((size_t)bt*1024 + n)*32);
        float o0 = bsp, o1 = 0.f;
        #pragma unroll
        for (int jj = 0; jj < 8; ++jj){
            uint4 rq = rp[jj];
            o0 = fdot2u(rq.x, wr[4*jj+0], o0);
            o1 = fdot2u(rq.y, wr[4*jj+1], o1);
            o0 = fdot2u(rq.z, wr[4*jj+2], o0);
            o1 = fdot2u(rq.w, wr[4*jj+3], o1);
        }
        size_t oidx = ((size_t)bt*1024 + n)*64 + l;
        out[oidx] = lrelu_(o0 + o1 + x[oidx]);
    }
}

extern "C" void kernel_launch(void* const* d_in, const int* in_sizes, int n_in,
                              void* d_out, int out_size, void* d_ws, size_t ws_size,
                              hipStream_t stream) {
    const float* x     = (const float*)d_in[0];
    const float* ne    = (const float*)d_in[1];
    const float* timeb = (const float*)d_in[2];
    const float* teb   = (const float*)d_in[3];
    const float* Wp    = (const float*)d_in[4];
    const float* bp    = (const float*)d_in[5];
    const float* tadj  = (const float*)d_in[6];
    const float* adj   = (const float*)d_in[7];
    const float* wspa  = (const float*)d_in[8];
    const float* bspa  = (const float*)d_in[9];

    float* out    = (float*)d_out;
    float* outc   = out  + (size_t)BT_*N_*64;      // c:   [BT,HS,N]
    float* outdyn = outc + (size_t)BT_*HS_*N_;     // dyn: [B,HT,TT]

    char* ws = (char*)d_ws;
    unsigned int* Ppk  = (unsigned int*)ws;                         // 25.2 MB
    float* dadj  = (float*)(ws + 25165824);                         // 12.6 MB
    float* tpart = dadj  + (size_t)BT_*HS_*N_;                      // 6.3 MB
    float* spart = tpart + (size_t)BT_*8*HS_*64;                    // 0.39 MB
    float* v1buf = spart + (size_t)BT_*8*64;
    float* vsum  = v1buf + (size_t)BT_*HS_*64;
    float* sbuf  = vsum  + (size_t)BT_*HS_*64;
    float* temb  = sbuf  + (size_t)BT_*HS_*64;
    float* v2    = temb  + (size_t)B_*HT_*64;
    unsigned int* recpk = (unsigned int*)(v2 + (size_t)BT_*HS_*64); // 25.2 MB

    k_P<<<dim3(BT_, 8), 256, 0, stream>>>(x, Wp, bp, Ppk);
    k_dadj<<<dim3(BT_, 16), 256, 0, stream>>>(teb, adj, dadj);

    // pass 0: c=softmax(dadj) -> test1; kB<0>: v1, v_r1 (uniform-c iter), vsum=v_r1
    kA<0><<<dim3(BT_, 8), 256, 0, stream>>>(Ppk, dadj, nullptr, tpart, spart, nullptr);
    kB<0><<<dim3(BT_), 256, 0, stream>>>(tpart, spart, v1buf, vsum, nullptr);

    // routing iters 2,3: logits = vsum.P
    kA<1><<<dim3(BT_, 8), 256, 0, stream>>>(Ppk, nullptr, vsum, tpart, nullptr, nullptr);
    kB<1><<<dim3(BT_), 256, 0, stream>>>(tpart, nullptr, v1buf, vsum, nullptr);
    kA<1><<<dim3(BT_, 8), 256, 0, stream>>>(Ppk, nullptr, vsum, tpart, nullptr, nullptr);
    kB<1><<<dim3(BT_), 256, 0, stream>>>(tpart, nullptr, v1buf, vsum, nullptr);

    // final: c = softmax(vsum.P + dadj); s
    kA<2><<<dim3(BT_, 8), 256, 0, stream>>>(Ppk, dadj, vsum, tpart, nullptr, outc);
    kB<2><<<dim3(BT_), 256, 0, stream>>>(tpart, nullptr, nullptr, nullptr, sbuf);

    k_dyn<<<dim3(B_, HT_), 192, 0, stream>>>(timeb, tadj, outdyn);
    k_tem<<<dim3(B_, 16), 256, 0, stream>>>(outdyn, sbuf, temb);
    k_retv2<<<dim3(B_, 48), 256, 0, stream>>>(outdyn, temb, sbuf, v2);
    k_rec<<<dim3(BT_, 8), 256, 0, stream>>>(outc, v2, recpk);
    k_final<<<dim3(N_), 256, 0, stream>>>(x, ne, wspa, bspa, recpk, out);
}

// Round 9
// 221.192 us; speedup vs baseline: 5.1206x; 1.0718x over previous
//
#include <hip/hip_runtime.h>
#include <math.h>

#define B_ 16
#define T_ 12
#define N_ 1024
#define D_ 64
#define HS_ 16
#define HT_ 64
#define TT_ 192
#define BT_ 192

typedef _Float16 f16x2 __attribute__((ext_vector_type(2)));

__device__ __forceinline__ unsigned int pkrtz(float a, float b){
    auto r = __builtin_amdgcn_cvt_pkrtz(a, b);
    return __builtin_bit_cast(unsigned int, r);
}
__device__ __forceinline__ float fdot2u(unsigned int a, unsigned int b, float c){
    return __builtin_amdgcn_fdot2(__builtin_bit_cast(f16x2, a),
                                  __builtin_bit_cast(f16x2, b), c, false);
}
__device__ __forceinline__ float loF(unsigned int a){ f16x2 h = __builtin_bit_cast(f16x2, a); return (float)h.x; }
__device__ __forceinline__ float hiF(unsigned int a){ f16x2 h = __builtin_bit_cast(f16x2, a); return (float)h.y; }

__device__ __forceinline__ float lrelu_(float v){ return v > 0.f ? v : 0.01f*v; }
__device__ __forceinline__ float squash_sc(float sn){ return (sn/(1.f+sn))/(sqrtf(sn)+1e-8f); }

__device__ __forceinline__ float wredsum64(float v){
    #pragma unroll
    for (int mk = 1; mk < 64; mk <<= 1) v += __shfl_xor(v, mk, 64);
    return v;
}

// ---------------------------------------------------------------------------
// k_P: P = squash(x@W^T+b) -> f16 d-pairs  Ppk[bt][n][32]   grid (192,8) x 256
// ---------------------------------------------------------------------------
__global__ __launch_bounds__(256, 1) void k_P(const float* __restrict__ x,
        const float* __restrict__ Wp, const float* __restrict__ bp,
        unsigned int* __restrict__ Ppk){
    __shared__ unsigned int xst[4][256];
    int w = threadIdx.x >> 6, l = threadIdx.x & 63;
    unsigned int wpk[32];
    #pragma unroll
    for (int j = 0; j < 32; ++j){
        float2 w2 = *(const float2*)(Wp + l*64 + 2*j);
        wpk[j] = pkrtz(w2.x, w2.y);
    }
    float bpd = bp[l];
    size_t rbase = ((size_t)blockIdx.x*1024 + blockIdx.y*128 + w*32);
    const float* xb = x + rbase*64;
    unsigned int* pb = Ppk + rbase*32;
    int half = l >> 5, j32 = l & 31;
    for (int bi = 0; bi < 4; ++bi){
        #pragma unroll
        for (int rr = 0; rr < 8; rr += 2){
            int row = bi*8 + rr + half;
            float2 xv = *(const float2*)(xb + row*64 + 2*j32);
            xst[w][(rr + half)*32 + j32] = pkrtz(xv.x, xv.y);
        }
        #pragma unroll
        for (int r = 0; r < 8; ++r){
            float y0 = 0.f, y1 = 0.f;
            #pragma unroll
            for (int jq = 0; jq < 8; ++jq){
                uint4 xa = *(uint4*)&xst[w][r*32 + 4*jq];
                y0 = fdot2u(xa.x, wpk[4*jq+0], y0);
                y1 = fdot2u(xa.y, wpk[4*jq+1], y1);
                y0 = fdot2u(xa.z, wpk[4*jq+2], y0);
                y1 = fdot2u(xa.w, wpk[4*jq+3], y1);
            }
            float y = bpd + y0 + y1;
            float sn = wredsum64(y*y);
            float p = y*squash_sc(sn);
            float po = __shfl_xor(p, 1, 64);
            if (!(l & 1)) pb[(bi*8 + r)*32 + (l>>1)] = pkrtz(p, po);
        }
    }
}

// ---------------------------------------------------------------------------
// k_dadj: dadj[bt,h,n] = sum_e teb[bt,e]*adj[e,h,n]   grid (192,16) x 256
// ---------------------------------------------------------------------------
__global__ __launch_bounds__(256) void k_dadj(const float* __restrict__ teb,
        const float* __restrict__ adj, float* __restrict__ dadj){
    int bt = blockIdx.x, h = blockIdx.y, n4 = threadIdx.x;
    float tl[16];
    #pragma unroll
    for (int e = 0; e < 16; ++e) tl[e] = teb[bt*16 + e];
    float4 acc = {0.f,0.f,0.f,0.f};
    #pragma unroll
    for (int e = 0; e < 16; ++e){
        float4 a = ((const float4*)(adj + ((size_t)(e*16 + h) << 10)))[n4];
        acc.x += tl[e]*a.x; acc.y += tl[e]*a.y; acc.z += tl[e]*a.z; acc.w += tl[e]*a.w;
    }
    ((float4*)(dadj + ((size_t)bt*16 + h)*1024))[n4] = acc;
}

// ---------------------------------------------------------------------------
// kA: one routing sweep over an n-chunk of 128.  grid (192,8) x 256
// Prologue (MODE!=0) folds the old kB: reduce tpIn -> t, finish v, vsum.
//   MODE 0: logits=dadj; write spOut (chunk sumP)
//   MODE 1: prologue {v1=squash(t); write v1buf; vr1=squash(v1*sp/16); vs=vr1}
//   MODE 2: prologue {v=squash(v1*t); vs=vsumIn+v}
//   MODE 3: like 2 but no vsum write; logits += dadj; write cout
// All: c=softmax_h(logits); partial t[h][d] -> tpOut[bt][ch]
// tpart/vsum are ping-ponged by the host to avoid intra-dispatch races.
// ---------------------------------------------------------------------------
template<int MODE>
__global__ __launch_bounds__(256, 2) void kA(const unsigned int* __restrict__ Ppk,
        const float* __restrict__ dadj,
        const float* __restrict__ tpIn, const float* __restrict__ spart,
        float* __restrict__ v1buf, const float* __restrict__ vsumIn,
        float* __restrict__ vsumOut,
        float* __restrict__ tpOut, float* __restrict__ spOut,
        float* __restrict__ cout){
    __shared__ unsigned int PL[128*36];   // f16 pairs, stride 36
    __shared__ unsigned int vLp[16*36];
    __shared__ float bL[16*130];
    __shared__ float cL[128*20];
    int bt = blockIdx.x, ch = blockIdx.y;
    int t = threadIdx.x, w = t >> 6, l = t & 63;
    int n0 = ch*128;

    const uint4* Pg = (const uint4*)(Ppk + ((size_t)bt*1024 + n0)*32);
    #pragma unroll
    for (int k = 0; k < 4; ++k){
        int idx4 = t + 256*k;
        uint4 u = Pg[idx4];
        *(uint4*)&PL[(idx4 >> 3)*36 + 4*(idx4 & 7)] = u;
    }
    if (MODE != 0){
        float sp = 0.f;
        if (MODE == 1){
            #pragma unroll
            for (int c = 0; c < 8; ++c) sp += spart[((size_t)bt*8 + c)*64 + l];
            sp *= (1.f/16.f);
        }
        #pragma unroll
        for (int i = 0; i < 4; ++i){
            int h = 4*w + i;
            float s = 0.f;
            #pragma unroll
            for (int c = 0; c < 8; ++c)
                s += tpIn[(((size_t)bt*8 + c)*16 + h)*64 + l];
            size_t oi = ((size_t)bt*16 + h)*64 + l;
            float vs;
            if (MODE == 1){
                float sn = wredsum64(s*s);
                float v1 = s*squash_sc(sn);
                v1buf[oi] = v1;
                float q = v1*sp;
                float sn2 = wredsum64(q*q);
                vs = q*squash_sc(sn2);
            } else {
                float q = v1buf[oi]*s;
                float sn = wredsum64(q*q);
                vs = vsumIn[oi] + q*squash_sc(sn);
            }
            if (MODE != 3) vsumOut[oi] = vs;
            float vo = __shfl_xor(vs, 1, 64);
            if (!(l & 1)) vLp[h*36 + (l >> 1)] = pkrtz(vs, vo);
        }
    }
    __syncthreads();

    // logits -> bL ; thread owns (n = t&127, hg = t>>7 covering 8 h)
    {
        int n = t & 127, hg = t >> 7;
        float acc8[8];
        #pragma unroll
        for (int i = 0; i < 8; ++i) acc8[i] = 0.f;
        if (MODE != 0){
            #pragma unroll
            for (int j = 0; j < 8; ++j){
                uint4 pq = *(uint4*)&PL[n*36 + 4*j];
                #pragma unroll
                for (int i = 0; i < 8; ++i){
                    uint4 vq = *(uint4*)&vLp[(hg*8 + i)*36 + 4*j];
                    acc8[i] = fdot2u(pq.x, vq.x, acc8[i]);
                    acc8[i] = fdot2u(pq.y, vq.y, acc8[i]);
                    acc8[i] = fdot2u(pq.z, vq.z, acc8[i]);
                    acc8[i] = fdot2u(pq.w, vq.w, acc8[i]);
                }
            }
        }
        if (MODE == 0 || MODE == 3){
            #pragma unroll
            for (int i = 0; i < 8; ++i)
                acc8[i] += dadj[((size_t)bt*16 + hg*8 + i)*1024 + n0 + n];
        }
        #pragma unroll
        for (int i = 0; i < 8; ++i) bL[(hg*8 + i)*130 + n] = acc8[i];
    }
    __syncthreads();

    // softmax over h per n
    if (t < 128){
        int n = t;
        float M = -1e30f;
        #pragma unroll
        for (int h = 0; h < 16; ++h) M = fmaxf(M, bL[h*130 + n]);
        float S = 0.f; float ev[16];
        #pragma unroll
        for (int h = 0; h < 16; ++h){ ev[h] = __expf(bL[h*130 + n] - M); S += ev[h]; }
        float inv = 1.f/S;
        #pragma unroll
        for (int h = 0; h < 16; ++h){
            float cv = ev[h]*inv;
            cL[n*20 + h] = cv;
            if (MODE == 3) cout[((size_t)bt*16 + h)*1024 + n0 + n] = cv;
        }
    }
    __syncthreads();

    // partial t[h][d]: wave w -> h 4w..4w+3, lane = d; sumP folded (MODE 0)
    float acc[4] = {0.f,0.f,0.f,0.f};
    float sp2 = 0.f;
    #pragma unroll 2
    for (int n = 0; n < 128; ++n){
        unsigned int pv = PL[n*36 + (l >> 1)];
        float p = (l & 1) ? hiF(pv) : loF(pv);
        float4 c4 = *(float4*)&cL[n*20 + 4*w];
        acc[0] += c4.x*p; acc[1] += c4.y*p; acc[2] += c4.z*p; acc[3] += c4.w*p;
        if (MODE == 0) sp2 += p;
    }
    #pragma unroll
    for (int i = 0; i < 4; ++i)
        tpOut[(((size_t)bt*8 + ch)*16 + 4*w + i)*64 + l] = acc[i];
    if (MODE == 0 && w == 0)
        spOut[((size_t)bt*8 + ch)*64 + l] = sp2;
}

// k_s: s = reduce tpart (raw)   grid 192 x 256
__global__ __launch_bounds__(256) void k_s(const float* __restrict__ tpart,
        float* __restrict__ sout){
    int bt = blockIdx.x;
    int w = threadIdx.x >> 6, l = threadIdx.x & 63;
    #pragma unroll
    for (int i = 0; i < 4; ++i){
        int h = 4*w + i;
        float s = 0.f;
        #pragma unroll
        for (int c = 0; c < 8; ++c)
            s += tpart[(((size_t)bt*8 + c)*16 + h)*64 + l];
        sout[((size_t)bt*16 + h)*64 + l] = s;
    }
}

// dyn[b,h,k] = sum_e time_eb[b,e]*t_adj[e,h,k]
__global__ __launch_bounds__(192) void k_dyn(const float* __restrict__ timeb,
        const float* __restrict__ tadj, float* __restrict__ dyn){
    int b = blockIdx.x, h = blockIdx.y, k = threadIdx.x;
    float acc = 0.f;
    #pragma unroll
    for (int e = 0; e < 16; ++e)
        acc += timeb[b*16+e]*tadj[((size_t)e*HT_+h)*TT_ + k];
    dyn[((size_t)b*HT_+h)*TT_ + k] = acc;
}

// tem[b,h,d] = lrelu( sum_k dyn[b,h,k]*(s[b,k,d] + mask[k>>4]) )  grid (16,16) x 256
__global__ __launch_bounds__(256) void k_tem(const float* __restrict__ dyn,
        const float* __restrict__ sbuf, float* __restrict__ tem){
    int b = blockIdx.x, hg = blockIdx.y;
    int w = threadIdx.x >> 6, l = threadIdx.x & 63;
    int h = hg*4 + w;
    const float* dr = dyn + ((size_t)b*HT_ + h)*TT_;
    const float* sb = sbuf + (size_t)b*TT_*64;
    float a0 = 0.f, a1 = 0.f;
    #pragma unroll 4
    for (int k = 0; k < TT_; k += 2){
        float m0 = (float)((k>>4)+1) * (1.f/12.f);
        float m1 = (float)(((k+1)>>4)+1) * (1.f/12.f);
        a0 += dr[k]   * (sb[(size_t)k*64 + l]     + m0);
        a1 += dr[k+1] * (sb[(size_t)(k+1)*64 + l] + m1);
    }
    tem[((size_t)b*HT_ + h)*64 + l] = lrelu_(a0 + a1);
}

// ret=lrelu(sum_h dyn*tem)+s; v2=squash(ret)   grid (16,48) x 256
__global__ __launch_bounds__(256) void k_retv2(const float* __restrict__ dyn,
        const float* __restrict__ temb, const float* __restrict__ sbuf,
        float* __restrict__ v2){
    int b = blockIdx.x, kg = blockIdx.y;
    int w = threadIdx.x >> 6, l = threadIdx.x & 63;
    int k = kg*4 + w;
    const float* tb = temb + (size_t)b*HT_*64;
    float a0 = 0.f, a1 = 0.f;
    #pragma unroll 4
    for (int h = 0; h < HT_; h += 2){
        a0 += dyn[((size_t)b*HT_ + h  )*TT_ + k] * tb[(size_t)h*64 + l];
        a1 += dyn[((size_t)b*HT_ + h+1)*TT_ + k] * tb[(size_t)(h+1)*64 + l];
    }
    float a = lrelu_(a0 + a1);
    float r = a + sbuf[((size_t)b*TT_ + k)*64 + l];
    float sn = wredsum64(r*r);
    v2[((size_t)b*TT_ + k)*64 + l] = r*squash_sc(sn);
}

// recon f16 pairs, layout [n][bt][32]: rec[n,bt,d] = sum_h c[bt,h,n]*v2[bt,h,d]
// grid (192,8) x 256
__global__ __launch_bounds__(256) void k_rec(const float* __restrict__ cbuf,
        const float* __restrict__ v2, unsigned int* __restrict__ recpk){
    __shared__ float vL[16*68];
    __shared__ float cL[16*132];
    int bt = blockIdx.x, nc = blockIdx.y;
    int t = threadIdx.x, l = t & 63, g = t >> 6;
    #pragma unroll
    for (int i = 0; i < 4; ++i){
        int idx = i*256 + t;
        vL[(idx>>6)*68 + (idx&63)] = v2[(size_t)bt*1024 + idx];
    }
    #pragma unroll
    for (int i = 0; i < 8; ++i){
        int idx = i*256 + t;
        cL[(idx>>7)*132 + (idx&127)] =
            cbuf[((size_t)bt*16 + (idx>>7))*1024 + nc*128 + (idx&127)];
    }
    __syncthreads();
    float vreg[16];
    #pragma unroll
    for (int h = 0; h < 16; ++h) vreg[h] = vL[h*68 + l];
    #pragma unroll 4
    for (int i = 0; i < 32; ++i){
        int nl = g + 4*i;
        float a = 0.f;
        #pragma unroll
        for (int h = 0; h < 16; ++h) a += cL[h*132 + nl]*vreg[h];
        float ap = __shfl_xor(a, 1, 64);
        if (!(l & 1))
            recpk[((size_t)(nc*128 + nl)*192 + bt)*32 + (l>>1)] = pkrtz(a, ap);
    }
}

// out = lrelu(rec @ wsp[n] + bsp[n] + x)   grid (1024,2) x 256
// rec rows staged in LDS (aliased with wsp scratch) -> no global latency in loop
__global__ __launch_bounds__(256) void k_final(const float* __restrict__ x,
        const float* __restrict__ ne, const float* __restrict__ wspa,
        const float* __restrict__ bspa, const unsigned int* __restrict__ recpk,
        float* __restrict__ out){
    __shared__ __align__(16) char uSm[17664];
    float* wspL = (float*)uSm;                       // [64][68]
    float* bspL = (float*)(uSm + 17408);             // [64]
    unsigned int* recL = (unsigned int*)uSm;         // [96][32] (phase B/C)
    int n = blockIdx.x, half = blockIdx.y;
    int t = threadIdx.x, l = t & 63, g = t >> 6;
    float nl16[16];
    #pragma unroll
    for (int e = 0; e < 16; ++e) nl16[e] = ne[n*16 + e];
    #pragma unroll
    for (int j = 0; j < 16; ++j){
        int io = j*256 + t;
        float a = 0.f;
        #pragma unroll
        for (int e = 0; e < 16; ++e) a += nl16[e]*wspa[(size_t)e*4096 + io];
        wspL[(io>>6)*68 + (io&63)] = a;
    }
    if (t < 64){
        float a = 0.f;
        #pragma unroll
        for (int e = 0; e < 16; ++e) a += nl16[e]*bspa[e*64 + t];
        bspL[t] = a;
    }
    __syncthreads();
    unsigned int wr[32];
    #pragma unroll
    for (int ip = 0; ip < 32; ++ip)
        wr[ip] = pkrtz(wspL[(2*ip)*68 + l], wspL[(2*ip+1)*68 + l]);
    float bsp = bspL[l];
    __syncthreads();    // all wspL reads done before recL overwrites
    // stage 96 rec rows: [n][half*96 .. half*96+96)[32]
    {
        const uint4* src = (const uint4*)(recpk + ((size_t)n*192 + half*96)*32);
        #pragma unroll
        for (int k = 0; k < 3; ++k)
            ((uint4*)recL)[t + 256*k] = src[t + 256*k];
    }
    __syncthreads();
    #pragma unroll 2
    for (int i = 0; i < 24; ++i){
        int r = i*4 + g;
        int bt = half*96 + r;
        const uint4* rp = (const uint4*)&recL[r*32];
        float o0 = bsp, o1 = 0.f;
        #pragma unroll
        for (int jj = 0; jj < 8; ++jj){
            uint4 rq = rp[jj];
            o0 = fdot2u(rq.x, wr[4*jj+0], o0);
            o1 = fdot2u(rq.y, wr[4*jj+1], o1);
            o0 = fdot2u(rq.z, wr[4*jj+2], o0);
            o1 = fdot2u(rq.w, wr[4*jj+3], o1);
        }
        size_t oidx = ((size_t)bt*1024 + n)*64 + l;
        out[oidx] = lrelu_(o0 + o1 + x[oidx]);
    }
}

extern "C" void kernel_launch(void* const* d_in, const int* in_sizes, int n_in,
                              void* d_out, int out_size, void* d_ws, size_t ws_size,
                              hipStream_t stream) {
    const float* x     = (const float*)d_in[0];
    const float* ne    = (const float*)d_in[1];
    const float* timeb = (const float*)d_in[2];
    const float* teb   = (const float*)d_in[3];
    const float* Wp    = (const float*)d_in[4];
    const float* bp    = (const float*)d_in[5];
    const float* tadj  = (const float*)d_in[6];
    const float* adj   = (const float*)d_in[7];
    const float* wspa  = (const float*)d_in[8];
    const float* bspa  = (const float*)d_in[9];

    float* out    = (float*)d_out;
    float* outc   = out  + (size_t)BT_*N_*64;      // c:   [BT,HS,N]
    float* outdyn = outc + (size_t)BT_*HS_*N_;     // dyn: [B,HT,TT]

    char* ws = (char*)d_ws;
    unsigned int* Ppk  = (unsigned int*)ws;                          // 25.2 MB
    float* dadj  = (float*)(ws + 25165824);                          // 12.6 MB
    float* tpA   = dadj  + (size_t)BT_*HS_*N_;                       // 6.3 MB
    float* tpB   = tpA   + (size_t)BT_*8*HS_*64;                     // 6.3 MB
    float* spart = tpB   + (size_t)BT_*8*HS_*64;                     // 0.39 MB
    float* v1buf = spart + (size_t)BT_*8*64;
    float* vs0   = v1buf + (size_t)BT_*HS_*64;
    float* vs1   = vs0   + (size_t)BT_*HS_*64;
    float* sbuf  = vs1   + (size_t)BT_*HS_*64;
    float* temb  = sbuf  + (size_t)BT_*HS_*64;
    float* v2    = temb  + (size_t)B_*HT_*64;
    unsigned int* recpk = (unsigned int*)(v2 + (size_t)BT_*HS_*64);  // 25.2 MB

    k_P<<<dim3(BT_, 8), 256, 0, stream>>>(x, Wp, bp, Ppk);
    k_dadj<<<dim3(BT_, 16), 256, 0, stream>>>(teb, adj, dadj);

    // pass 0: c=softmax(dadj) -> test1 partials (tpA) + sumP chunks
    kA<0><<<dim3(BT_, 8), 256, 0, stream>>>(Ppk, dadj, nullptr, nullptr,
            nullptr, nullptr, nullptr, tpA, spart, nullptr);
    // iter1(fold)+iter2: prologue {v1, vr1=vs0}; c2; t2 -> tpB
    kA<1><<<dim3(BT_, 8), 256, 0, stream>>>(Ppk, nullptr, tpA, spart,
            v1buf, nullptr, vs0, tpB, nullptr, nullptr);
    // iter3: prologue {v2; vs1=vs0+v2}; c3; t3 -> tpA
    kA<2><<<dim3(BT_, 8), 256, 0, stream>>>(Ppk, nullptr, tpB, nullptr,
            v1buf, vs0, vs1, tpA, nullptr, nullptr);
    // final: prologue {v3; vs=vs1+v3}; c=softmax(vs.P+dadj) -> outc; s -> tpB
    kA<3><<<dim3(BT_, 8), 256, 0, stream>>>(Ppk, dadj, tpA, nullptr,
            v1buf, vs1, nullptr, tpB, nullptr, outc);
    k_s<<<dim3(BT_), 256, 0, stream>>>(tpB, sbuf);

    k_dyn<<<dim3(B_, HT_), 192, 0, stream>>>(timeb, tadj, outdyn);
    k_tem<<<dim3(B_, 16), 256, 0, stream>>>(outdyn, sbuf, temb);
    k_retv2<<<dim3(B_, 48), 256, 0, stream>>>(outdyn, temb, sbuf, v2);
    k_rec<<<dim3(BT_, 8), 256, 0, stream>>>(outc, v2, recpk);
    k_final<<<dim3(N_, 2), 256, 0, stream>>>(x, ne, wspa, bspa, recpk, out);
}

// Round 10
// 213.587 us; speedup vs baseline: 5.3029x; 1.0356x over previous
//
#include <hip/hip_runtime.h>
#include <math.h>

#define B_ 16
#define T_ 12
#define N_ 1024
#define D_ 64
#define HS_ 16
#define HT_ 64
#define TT_ 192
#define BT_ 192

typedef _Float16 f16x2 __attribute__((ext_vector_type(2)));

__device__ __forceinline__ unsigned int pkrtz(float a, float b){
    auto r = __builtin_amdgcn_cvt_pkrtz(a, b);
    return __builtin_bit_cast(unsigned int, r);
}
__device__ __forceinline__ float fdot2u(unsigned int a, unsigned int b, float c){
    return __builtin_amdgcn_fdot2(__builtin_bit_cast(f16x2, a),
                                  __builtin_bit_cast(f16x2, b), c, false);
}
__device__ __forceinline__ float loF(unsigned int a){ f16x2 h = __builtin_bit_cast(f16x2, a); return (float)h.x; }
__device__ __forceinline__ float hiF(unsigned int a){ f16x2 h = __builtin_bit_cast(f16x2, a); return (float)h.y; }

__device__ __forceinline__ float lrelu_(float v){ return v > 0.f ? v : 0.01f*v; }
__device__ __forceinline__ float squash_sc(float sn){ return (sn/(1.f+sn))/(sqrtf(sn)+1e-8f); }

__device__ __forceinline__ float wredsum64(float v){
    #pragma unroll
    for (int mk = 1; mk < 64; mk <<= 1) v += __shfl_xor(v, mk, 64);
    return v;
}

// ---------------------------------------------------------------------------
// k_wpack: Wpk2[d*32+j] = f16pair(Wp[d][2j], Wp[d][2j+1])   1 block x 256
// ---------------------------------------------------------------------------
__global__ __launch_bounds__(256) void k_wpack(const float* __restrict__ Wp,
        unsigned int* __restrict__ Wpk2){
    int t = threadIdx.x;
    #pragma unroll
    for (int i = 0; i < 8; ++i){
        int idx = i*256 + t;
        float2 w2 = *(const float2*)(Wp + 2*idx);
        Wpk2[idx] = pkrtz(w2.x, w2.y);
    }
}

// ---------------------------------------------------------------------------
// k_P: P = squash(x@W^T+b) -> f16 d-pairs Ppk[bt][n][32]   grid (192,4) x 256
// Lane-per-row: no cross-lane reduce (round-9 counters: 7 ds_swizzle serial
// chain per row was the bottleneck, 51us @ VALU 53%). W via uniform->SGPR
// loads, x row in 32 packed-f16 regs via swizzled LDS stage.
// ---------------------------------------------------------------------------
__global__ __launch_bounds__(256, 1) void k_P(const float* __restrict__ x,
        const unsigned int* __restrict__ Wpk2, const float* __restrict__ bp,
        unsigned int* __restrict__ Ppk){
    __shared__ unsigned int xst[4][64*33];
    int w = threadIdx.x >> 6, l = threadIdx.x & 63;
    size_t rbase = (size_t)blockIdx.x*1024 + blockIdx.y*256 + w*64;
    const float* xb = x + rbase*64;
    // stage 64 rows (f16 pairs), swizzle stride 33
    #pragma unroll
    for (int j = 0; j < 32; ++j){
        int idx = j*64 + l;          // 0..2047
        int row = idx >> 5, cp = idx & 31;
        float2 xv = *(const float2*)(xb + row*64 + 2*cp);
        xst[w][row*33 + cp] = pkrtz(xv.x, xv.y);
    }
    // own row into regs (same wave wrote it; compiler inserts lgkmcnt)
    unsigned int xr[32];
    #pragma unroll
    for (int j = 0; j < 32; ++j) xr[j] = xst[w][l*33 + j];

    float sn = 0.f;
    unsigned int ypk[32];
    #pragma unroll 4
    for (int d2 = 0; d2 < 32; ++d2){
        float y0 = bp[2*d2], y1 = bp[2*d2+1];
        float y0b = 0.f, y1b = 0.f;
        const uint4* wr0 = (const uint4*)(Wpk2 + (2*d2)*32);
        const uint4* wr1 = (const uint4*)(Wpk2 + (2*d2+1)*32);
        #pragma unroll
        for (int jq = 0; jq < 8; ++jq){
            uint4 w0 = wr0[jq], w1 = wr1[jq];
            uint4 xa = *(uint4*)&xr[4*jq];
            y0  = fdot2u(xa.x, w0.x, y0);  y0b = fdot2u(xa.y, w0.y, y0b);
            y0  = fdot2u(xa.z, w0.z, y0);  y0b = fdot2u(xa.w, w0.w, y0b);
            y1  = fdot2u(xa.x, w1.x, y1);  y1b = fdot2u(xa.y, w1.y, y1b);
            y1  = fdot2u(xa.z, w1.z, y1);  y1b = fdot2u(xa.w, w1.w, y1b);
        }
        float ya = y0 + y0b, yb = y1 + y1b;
        sn += ya*ya + yb*yb;
        ypk[d2] = pkrtz(ya, yb);
    }
    float sc = squash_sc(sn);
    #pragma unroll
    for (int d2 = 0; d2 < 32; ++d2)
        ypk[d2] = pkrtz(loF(ypk[d2])*sc, hiF(ypk[d2])*sc);
    unsigned int* pb = Ppk + (rbase + l)*32;
    #pragma unroll
    for (int q = 0; q < 8; ++q)
        ((uint4*)pb)[q] = *(uint4*)&ypk[4*q];
}

// ---------------------------------------------------------------------------
// kA: one routing sweep over an n-chunk of 128.  grid (192,8) x 256
//   MODE 0: logits=dadj computed inline from teb/adj (written to dadjb);
//           also writes spOut (chunk sumP)
//   MODE 1: prologue {v1=squash(t); vr1=squash(v1*sp/16); vs=vr1}
//   MODE 2: prologue {v=squash(v1*t); vs=vsumIn+v}
//   MODE 3: like 2 but no vsum write; logits += dadjb; write cout
// All: c=softmax_h(logits); partial t[h][d] -> tpOut[bt][ch]
// ---------------------------------------------------------------------------
template<int MODE>
__global__ __launch_bounds__(256, 2) void kA(const unsigned int* __restrict__ Ppk,
        const float* __restrict__ teb, const float* __restrict__ adj,
        float* __restrict__ dadjb,
        const float* __restrict__ tpIn, const float* __restrict__ spart,
        float* __restrict__ v1buf, const float* __restrict__ vsumIn,
        float* __restrict__ vsumOut,
        float* __restrict__ tpOut, float* __restrict__ spOut,
        float* __restrict__ cout){
    __shared__ unsigned int PL[128*36];   // f16 pairs, stride 36
    __shared__ unsigned int vLp[16*36];
    __shared__ float bL[16*130];
    __shared__ float cL[128*20];
    int bt = blockIdx.x, ch = blockIdx.y;
    int t = threadIdx.x, w = t >> 6, l = t & 63;
    int n0 = ch*128;

    const uint4* Pg = (const uint4*)(Ppk + ((size_t)bt*1024 + n0)*32);
    #pragma unroll
    for (int k = 0; k < 4; ++k){
        int idx4 = t + 256*k;
        uint4 u = Pg[idx4];
        *(uint4*)&PL[(idx4 >> 3)*36 + 4*(idx4 & 7)] = u;
    }
    if (MODE != 0){
        float sp = 0.f;
        if (MODE == 1){
            #pragma unroll
            for (int c = 0; c < 8; ++c) sp += spart[((size_t)bt*8 + c)*64 + l];
            sp *= (1.f/16.f);
        }
        #pragma unroll
        for (int i = 0; i < 4; ++i){
            int h = 4*w + i;
            float s = 0.f;
            #pragma unroll
            for (int c = 0; c < 8; ++c)
                s += tpIn[(((size_t)bt*8 + c)*16 + h)*64 + l];
            size_t oi = ((size_t)bt*16 + h)*64 + l;
            float vs;
            if (MODE == 1){
                float sn = wredsum64(s*s);
                float v1 = s*squash_sc(sn);
                v1buf[oi] = v1;
                float q = v1*sp;
                float sn2 = wredsum64(q*q);
                vs = q*squash_sc(sn2);
            } else {
                float q = v1buf[oi]*s;
                float sn = wredsum64(q*q);
                vs = vsumIn[oi] + q*squash_sc(sn);
            }
            if (MODE != 3) vsumOut[oi] = vs;
            float vo = __shfl_xor(vs, 1, 64);
            if (!(l & 1)) vLp[h*36 + (l >> 1)] = pkrtz(vs, vo);
        }
    }
    __syncthreads();

    // logits -> bL ; thread owns (n = t&127, hg = t>>7 covering 8 h)
    {
        int n = t & 127, hg = t >> 7;
        float acc8[8];
        #pragma unroll
        for (int i = 0; i < 8; ++i) acc8[i] = 0.f;
        if (MODE != 0){
            #pragma unroll
            for (int j = 0; j < 8; ++j){
                uint4 pq = *(uint4*)&PL[n*36 + 4*j];
                #pragma unroll
                for (int i = 0; i < 8; ++i){
                    uint4 vq = *(uint4*)&vLp[(hg*8 + i)*36 + 4*j];
                    acc8[i] = fdot2u(pq.x, vq.x, acc8[i]);
                    acc8[i] = fdot2u(pq.y, vq.y, acc8[i]);
                    acc8[i] = fdot2u(pq.z, vq.z, acc8[i]);
                    acc8[i] = fdot2u(pq.w, vq.w, acc8[i]);
                }
            }
        }
        if (MODE == 0){
            float tl[16];
            #pragma unroll
            for (int e = 0; e < 16; ++e) tl[e] = teb[bt*16 + e];
            #pragma unroll
            for (int i = 0; i < 8; ++i){
                int h = hg*8 + i;
                float s = 0.f;
                #pragma unroll
                for (int e = 0; e < 16; ++e)
                    s += tl[e]*adj[(((e << 4) + h) << 10) + n0 + n];
                acc8[i] = s;
                dadjb[((size_t)bt*16 + h)*1024 + n0 + n] = s;
            }
        }
        if (MODE == 3){
            #pragma unroll
            for (int i = 0; i < 8; ++i)
                acc8[i] += dadjb[((size_t)bt*16 + hg*8 + i)*1024 + n0 + n];
        }
        #pragma unroll
        for (int i = 0; i < 8; ++i) bL[(hg*8 + i)*130 + n] = acc8[i];
    }
    __syncthreads();

    // softmax over h per n
    if (t < 128){
        int n = t;
        float M = -1e30f;
        #pragma unroll
        for (int h = 0; h < 16; ++h) M = fmaxf(M, bL[h*130 + n]);
        float S = 0.f; float ev[16];
        #pragma unroll
        for (int h = 0; h < 16; ++h){ ev[h] = __expf(bL[h*130 + n] - M); S += ev[h]; }
        float inv = 1.f/S;
        #pragma unroll
        for (int h = 0; h < 16; ++h){
            float cv = ev[h]*inv;
            cL[n*20 + h] = cv;
            if (MODE == 3) cout[((size_t)bt*16 + h)*1024 + n0 + n] = cv;
        }
    }
    __syncthreads();

    // partial t[h][d]: wave w -> h 4w..4w+3, lane = d; sumP folded (MODE 0)
    float acc[4] = {0.f,0.f,0.f,0.f};
    float sp2 = 0.f;
    #pragma unroll 2
    for (int n = 0; n < 128; ++n){
        unsigned int pv = PL[n*36 + (l >> 1)];
        float p = (l & 1) ? hiF(pv) : loF(pv);
        float4 c4 = *(float4*)&cL[n*20 + 4*w];
        acc[0] += c4.x*p; acc[1] += c4.y*p; acc[2] += c4.z*p; acc[3] += c4.w*p;
        if (MODE == 0) sp2 += p;
    }
    #pragma unroll
    for (int i = 0; i < 4; ++i)
        tpOut[(((size_t)bt*8 + ch)*16 + 4*w + i)*64 + l] = acc[i];
    if (MODE == 0 && w == 0)
        spOut[((size_t)bt*8 + ch)*64 + l] = sp2;
}

// k_s: s = reduce tpart (raw)   grid 192 x 256
__global__ __launch_bounds__(256) void k_s(const float* __restrict__ tpart,
        float* __restrict__ sout){
    int bt = blockIdx.x;
    int w = threadIdx.x >> 6, l = threadIdx.x & 63;
    #pragma unroll
    for (int i = 0; i < 4; ++i){
        int h = 4*w + i;
        float s = 0.f;
        #pragma unroll
        for (int c = 0; c < 8; ++c)
            s += tpart[(((size_t)bt*8 + c)*16 + h)*64 + l];
        sout[((size_t)bt*16 + h)*64 + l] = s;
    }
}

// k_dyntem: fused dyn + tem.  grid (16,64) x 256
// phase1: dyn[b,h,k] (t<192); phase2: tem[b,h,d]=lrelu(sum_k dyn*(s+mask))
__global__ __launch_bounds__(256) void k_dyntem(const float* __restrict__ timeb,
        const float* __restrict__ tadj, const float* __restrict__ sbuf,
        float* __restrict__ dyn, float* __restrict__ tem){
    __shared__ float dynL[192];
    __shared__ float part[4][64];
    int b = blockIdx.x, h = blockIdx.y, t = threadIdx.x;
    if (t < 192){
        float a = 0.f;
        #pragma unroll
        for (int e = 0; e < 16; ++e)
            a += timeb[b*16 + e]*tadj[((size_t)e*HT_ + h)*TT_ + t];
        dynL[t] = a;
        dyn[((size_t)b*HT_ + h)*TT_ + t] = a;
    }
    __syncthreads();
    int p = t >> 6, d = t & 63;
    const float* sb = sbuf + (size_t)b*TT_*64;
    float a = 0.f;
    #pragma unroll 4
    for (int k = 48*p; k < 48*p + 48; ++k)
        a += dynL[k]*(sb[(size_t)k*64 + d] + (float)((k >> 4) + 1)*(1.f/12.f));
    part[p][d] = a;
    __syncthreads();
    if (t < 64)
        tem[((size_t)b*HT_ + h)*64 + t] =
            lrelu_(part[0][t] + part[1][t] + part[2][t] + part[3][t]);
}

// ret=lrelu(sum_h dyn*tem)+s; v2=squash(ret)   grid (16,48) x 256
__global__ __launch_bounds__(256) void k_retv2(const float* __restrict__ dyn,
        const float* __restrict__ temb, const float* __restrict__ sbuf,
        float* __restrict__ v2){
    int b = blockIdx.x, kg = blockIdx.y;
    int w = threadIdx.x >> 6, l = threadIdx.x & 63;
    int k = kg*4 + w;
    const float* tb = temb + (size_t)b*HT_*64;
    float a0 = 0.f, a1 = 0.f;
    #pragma unroll 4
    for (int h = 0; h < HT_; h += 2){
        a0 += dyn[((size_t)b*HT_ + h  )*TT_ + k] * tb[(size_t)h*64 + l];
        a1 += dyn[((size_t)b*HT_ + h+1)*TT_ + k] * tb[(size_t)(h+1)*64 + l];
    }
    float a = lrelu_(a0 + a1);
    float r = a + sbuf[((size_t)b*TT_ + k)*64 + l];
    float sn = wredsum64(r*r);
    v2[((size_t)b*TT_ + k)*64 + l] = r*squash_sc(sn);
}

// recon f16 pairs, layout [n][bt][32]: rec[n,bt,d] = sum_h c[bt,h,n]*v2[bt,h,d]
// grid (192,8) x 256
__global__ __launch_bounds__(256) void k_rec(const float* __restrict__ cbuf,
        const float* __restrict__ v2, unsigned int* __restrict__ recpk){
    __shared__ float vL[16*68];
    __shared__ float cL[16*132];
    int bt = blockIdx.x, nc = blockIdx.y;
    int t = threadIdx.x, l = t & 63, g = t >> 6;
    #pragma unroll
    for (int i = 0; i < 4; ++i){
        int idx = i*256 + t;
        vL[(idx>>6)*68 + (idx&63)] = v2[(size_t)bt*1024 + idx];
    }
    #pragma unroll
    for (int i = 0; i < 8; ++i){
        int idx = i*256 + t;
        cL[(idx>>7)*132 + (idx&127)] =
            cbuf[((size_t)bt*16 + (idx>>7))*1024 + nc*128 + (idx&127)];
    }
    __syncthreads();
    float vreg[16];
    #pragma unroll
    for (int h = 0; h < 16; ++h) vreg[h] = vL[h*68 + l];
    #pragma unroll 4
    for (int i = 0; i < 32; ++i){
        int nl = g + 4*i;
        float a = 0.f;
        #pragma unroll
        for (int h = 0; h < 16; ++h) a += cL[h*132 + nl]*vreg[h];
        float ap = __shfl_xor(a, 1, 64);
        if (!(l & 1))
            recpk[((size_t)(nc*128 + nl)*192 + bt)*32 + (l>>1)] = pkrtz(a, ap);
    }
}

// out = lrelu(rec @ wsp[n] + bsp[n] + x)   grid (1024,2) x 256
__global__ __launch_bounds__(256) void k_final(const float* __restrict__ x,
        const float* __restrict__ ne, const float* __restrict__ wspa,
        const float* __restrict__ bspa, const unsigned int* __restrict__ recpk,
        float* __restrict__ out){
    __shared__ __align__(16) char uSm[17664];
    float* wspL = (float*)uSm;                       // [64][68]
    float* bspL = (float*)(uSm + 17408);             // [64]
    unsigned int* recL = (unsigned int*)uSm;         // [96][32] (phase B/C)
    int n = blockIdx.x, half = blockIdx.y;
    int t = threadIdx.x, l = t & 63, g = t >> 6;
    float nl16[16];
    #pragma unroll
    for (int e = 0; e < 16; ++e) nl16[e] = ne[n*16 + e];
    #pragma unroll
    for (int j = 0; j < 16; ++j){
        int io = j*256 + t;
        float a = 0.f;
        #pragma unroll
        for (int e = 0; e < 16; ++e) a += nl16[e]*wspa[(size_t)e*4096 + io];
        wspL[(io>>6)*68 + (io&63)] = a;
    }
    if (t < 64){
        float a = 0.f;
        #pragma unroll
        for (int e = 0; e < 16; ++e) a += nl16[e]*bspa[e*64 + t];
        bspL[t] = a;
    }
    __syncthreads();
    unsigned int wr[32];
    #pragma unroll
    for (int ip = 0; ip < 32; ++ip)
        wr[ip] = pkrtz(wspL[(2*ip)*68 + l], wspL[(2*ip+1)*68 + l]);
    float bsp = bspL[l];
    __syncthreads();
    {
        const uint4* src = (const uint4*)(recpk + ((size_t)n*192 + half*96)*32);
        #pragma unroll
        for (int k = 0; k < 3; ++k)
            ((uint4*)recL)[t + 256*k] = src[t + 256*k];
    }
    __syncthreads();
    #pragma unroll 2
    for (int i = 0; i < 24; ++i){
        int r = i*4 + g;
        int bt = half*96 + r;
        const uint4* rp = (const uint4*)&recL[r*32];
        float o0 = bsp, o1 = 0.f;
        #pragma unroll
        for (int jj = 0; jj < 8; ++jj){
            uint4 rq = rp[jj];
            o0 = fdot2u(rq.x, wr[4*jj+0], o0);
            o1 = fdot2u(rq.y, wr[4*jj+1], o1);
            o0 = fdot2u(rq.z, wr[4*jj+2], o0);
            o1 = fdot2u(rq.w, wr[4*jj+3], o1);
        }
        size_t oidx = ((size_t)bt*1024 + n)*64 + l;
        out[oidx] = lrelu_(o0 + o1 + x[oidx]);
    }
}

extern "C" void kernel_launch(void* const* d_in, const int* in_sizes, int n_in,
                              void* d_out, int out_size, void* d_ws, size_t ws_size,
                              hipStream_t stream) {
    const float* x     = (const float*)d_in[0];
    const float* ne    = (const float*)d_in[1];
    const float* timeb = (const float*)d_in[2];
    const float* teb   = (const float*)d_in[3];
    const float* Wp    = (const float*)d_in[4];
    const float* bp    = (const float*)d_in[5];
    const float* tadj  = (const float*)d_in[6];
    const float* adj   = (const float*)d_in[7];
    const float* wspa  = (const float*)d_in[8];
    const float* bspa  = (const float*)d_in[9];

    float* out    = (float*)d_out;
    float* outc   = out  + (size_t)BT_*N_*64;      // c:   [BT,HS,N]
    float* outdyn = outc + (size_t)BT_*HS_*N_;     // dyn: [B,HT,TT]

    char* ws = (char*)d_ws;
    unsigned int* Ppk  = (unsigned int*)ws;                          // 25.2 MB
    float* dadj  = (float*)(ws + 25165824);                          // 12.6 MB
    float* tpA   = dadj  + (size_t)BT_*HS_*N_;                       // 6.3 MB
    float* tpB   = tpA   + (size_t)BT_*8*HS_*64;                     // 6.3 MB
    float* spart = tpB   + (size_t)BT_*8*HS_*64;                     // 0.39 MB
    float* v1buf = spart + (size_t)BT_*8*64;
    float* vs0   = v1buf + (size_t)BT_*HS_*64;
    float* vs1   = vs0   + (size_t)BT_*HS_*64;
    float* sbuf  = vs1   + (size_t)BT_*HS_*64;
    float* temb  = sbuf  + (size_t)BT_*HS_*64;
    float* v2    = temb  + (size_t)B_*HT_*64;
    unsigned int* recpk = (unsigned int*)(v2 + (size_t)BT_*HS_*64);  // 25.2 MB
    unsigned int* Wpk2  = recpk + (size_t)N_*BT_*32;                 // 8 KB

    k_wpack<<<dim3(1), 256, 0, stream>>>(Wp, Wpk2);
    k_P<<<dim3(BT_, 4), 256, 0, stream>>>(x, Wpk2, bp, Ppk);

    // pass 0: logits = dadj (computed inline, stored); t partials + sumP chunks
    kA<0><<<dim3(BT_, 8), 256, 0, stream>>>(Ppk, teb, adj, dadj, nullptr,
            nullptr, nullptr, nullptr, nullptr, tpA, spart, nullptr);
    // iter1(fold)+iter2: prologue {v1, vr1=vs0}; c2; t2 -> tpB
    kA<1><<<dim3(BT_, 8), 256, 0, stream>>>(Ppk, teb, adj, dadj, tpA,
            spart, v1buf, nullptr, vs0, tpB, nullptr, nullptr);
    // iter3: prologue {v2; vs1=vs0+v2}; c3; t3 -> tpA
    kA<2><<<dim3(BT_, 8), 256, 0, stream>>>(Ppk, teb, adj, dadj, tpB,
            nullptr, v1buf, vs0, vs1, tpA, nullptr, nullptr);
    // final: prologue {v3; vs=vs1+v3}; c=softmax(vs.P+dadj) -> outc; s -> tpB
    kA<3><<<dim3(BT_, 8), 256, 0, stream>>>(Ppk, teb, adj, dadj, tpA,
            nullptr, v1buf, vs1, nullptr, tpB, nullptr, outc);
    k_s<<<dim3(BT_), 256, 0, stream>>>(tpB, sbuf);

    k_dyntem<<<dim3(B_, HT_), 256, 0, stream>>>(timeb, tadj, sbuf, outdyn, temb);
    k_retv2<<<dim3(B_, 48), 256, 0, stream>>>(outdyn, temb, sbuf, v2);
    k_rec<<<dim3(BT_, 8), 256, 0, stream>>>(outc, v2, recpk);
    k_final<<<dim3(N_, 2), 256, 0, stream>>>(x, ne, wspa, bspa, recpk, out);
}

// Round 11
// 208.729 us; speedup vs baseline: 5.4264x; 1.0233x over previous
//
#include <hip/hip_runtime.h>
#include <math.h>

#define B_ 16
#define T_ 12
#define N_ 1024
#define D_ 64
#define HS_ 16
#define HT_ 64
#define TT_ 192
#define BT_ 192

typedef _Float16 f16x2 __attribute__((ext_vector_type(2)));

__device__ __forceinline__ unsigned int pkrtz(float a, float b){
    auto r = __builtin_amdgcn_cvt_pkrtz(a, b);
    return __builtin_bit_cast(unsigned int, r);
}
__device__ __forceinline__ float fdot2u(unsigned int a, unsigned int b, float c){
    return __builtin_amdgcn_fdot2(__builtin_bit_cast(f16x2, a),
                                  __builtin_bit_cast(f16x2, b), c, false);
}
__device__ __forceinline__ float loF(unsigned int a){ f16x2 h = __builtin_bit_cast(f16x2, a); return (float)h.x; }
__device__ __forceinline__ float hiF(unsigned int a){ f16x2 h = __builtin_bit_cast(f16x2, a); return (float)h.y; }

__device__ __forceinline__ float lrelu_(float v){ return v > 0.f ? v : 0.01f*v; }
__device__ __forceinline__ float squash_sc(float sn){ return (sn/(1.f+sn))/(sqrtf(sn)+1e-8f); }

__device__ __forceinline__ float wredsum64(float v){
    #pragma unroll
    for (int mk = 1; mk < 64; mk <<= 1) v += __shfl_xor(v, mk, 64);
    return v;
}

// ---------------------------------------------------------------------------
// k_wpack: Wpk2[d*32+j] = f16pair(Wp[d][2j], Wp[d][2j+1])   1 block x 256
// ---------------------------------------------------------------------------
__global__ __launch_bounds__(256) void k_wpack(const float* __restrict__ Wp,
        unsigned int* __restrict__ Wpk2){
    int t = threadIdx.x;
    #pragma unroll
    for (int i = 0; i < 8; ++i){
        int idx = i*256 + t;
        float2 w2 = *(const float2*)(Wp + 2*idx);
        Wpk2[idx] = pkrtz(w2.x, w2.y);
    }
}

// ---------------------------------------------------------------------------
// k_P: P = squash(x@W^T+b) -> f16 d-pairs Ppk[bt][n][32]   grid (192,4) x 256
// Lane-per-row, NO cross-lane reduce. Round-10 lesson (rule #20): the d2 loop
// MUST be fully unrolled — partial unroll leaves ypk[]/xr[] runtime-indexed
// -> scratch (52 VGPR, +43MB spill traffic). Full unroll -> all reg-resident.
// ---------------------------------------------------------------------------
__global__ __launch_bounds__(256, 1) void k_P(const float* __restrict__ x,
        const unsigned int* __restrict__ Wpk2, const float* __restrict__ bp,
        unsigned int* __restrict__ Ppk){
    __shared__ unsigned int xst[4][64*33];
    int w = threadIdx.x >> 6, l = threadIdx.x & 63;
    size_t rbase = (size_t)blockIdx.x*1024 + blockIdx.y*256 + w*64;
    const float* xb = x + rbase*64;
    // stage 64 rows (f16 pairs), swizzle stride 33
    #pragma unroll
    for (int j = 0; j < 32; ++j){
        int idx = j*64 + l;          // 0..2047
        int row = idx >> 5, cp = idx & 31;
        float2 xv = *(const float2*)(xb + row*64 + 2*cp);
        xst[w][row*33 + cp] = pkrtz(xv.x, xv.y);
    }
    // own row into regs (same wave wrote it; compiler inserts lgkmcnt)
    unsigned int xr[32];
    #pragma unroll
    for (int j = 0; j < 32; ++j) xr[j] = xst[w][l*33 + j];

    float sn = 0.f;
    unsigned int ypk[32];
    #pragma unroll
    for (int d2 = 0; d2 < 32; ++d2){
        float y0 = bp[2*d2], y1 = bp[2*d2+1];
        float y0b = 0.f, y1b = 0.f;
        const uint4* wr0 = (const uint4*)(Wpk2 + (2*d2)*32);
        const uint4* wr1 = (const uint4*)(Wpk2 + (2*d2+1)*32);
        #pragma unroll
        for (int jq = 0; jq < 8; ++jq){
            uint4 w0 = wr0[jq], w1 = wr1[jq];
            uint4 xa = *(uint4*)&xr[4*jq];
            y0  = fdot2u(xa.x, w0.x, y0);  y0b = fdot2u(xa.y, w0.y, y0b);
            y0  = fdot2u(xa.z, w0.z, y0);  y0b = fdot2u(xa.w, w0.w, y0b);
            y1  = fdot2u(xa.x, w1.x, y1);  y1b = fdot2u(xa.y, w1.y, y1b);
            y1  = fdot2u(xa.z, w1.z, y1);  y1b = fdot2u(xa.w, w1.w, y1b);
        }
        float ya = y0 + y0b, yb = y1 + y1b;
        sn += ya*ya + yb*yb;
        ypk[d2] = pkrtz(ya, yb);
    }
    float sc = squash_sc(sn);
    #pragma unroll
    for (int d2 = 0; d2 < 32; ++d2)
        ypk[d2] = pkrtz(loF(ypk[d2])*sc, hiF(ypk[d2])*sc);
    unsigned int* pb = Ppk + (rbase + l)*32;
    #pragma unroll
    for (int q = 0; q < 8; ++q)
        ((uint4*)pb)[q] = *(uint4*)&ypk[4*q];
}

// ---------------------------------------------------------------------------
// kA: one routing sweep over an n-chunk of 128.  grid (192,8) x 256
//   MODE 0: logits=dadj computed inline from teb/adj (written to dadjb);
//           also writes spOut (chunk sumP)
//   MODE 1: prologue {v1=squash(t); vr1=squash(v1*sp/16); vs=vr1}
//   MODE 2: prologue {v=squash(v1*t); vs=vsumIn+v}
//   MODE 3: like 2 but no vsum write; logits += dadjb; write cout
// All: c=softmax_h(logits); partial t[h][d] -> tpOut[bt][ch]
// ---------------------------------------------------------------------------
template<int MODE>
__global__ __launch_bounds__(256, 2) void kA(const unsigned int* __restrict__ Ppk,
        const float* __restrict__ teb, const float* __restrict__ adj,
        float* __restrict__ dadjb,
        const float* __restrict__ tpIn, const float* __restrict__ spart,
        float* __restrict__ v1buf, const float* __restrict__ vsumIn,
        float* __restrict__ vsumOut,
        float* __restrict__ tpOut, float* __restrict__ spOut,
        float* __restrict__ cout){
    __shared__ unsigned int PL[128*36];   // f16 pairs, stride 36
    __shared__ unsigned int vLp[16*36];
    __shared__ float bL[16*130];
    __shared__ float cL[128*20];
    int bt = blockIdx.x, ch = blockIdx.y;
    int t = threadIdx.x, w = t >> 6, l = t & 63;
    int n0 = ch*128;

    const uint4* Pg = (const uint4*)(Ppk + ((size_t)bt*1024 + n0)*32);
    #pragma unroll
    for (int k = 0; k < 4; ++k){
        int idx4 = t + 256*k;
        uint4 u = Pg[idx4];
        *(uint4*)&PL[(idx4 >> 3)*36 + 4*(idx4 & 7)] = u;
    }
    if (MODE != 0){
        float sp = 0.f;
        if (MODE == 1){
            #pragma unroll
            for (int c = 0; c < 8; ++c) sp += spart[((size_t)bt*8 + c)*64 + l];
            sp *= (1.f/16.f);
        }
        #pragma unroll
        for (int i = 0; i < 4; ++i){
            int h = 4*w + i;
            float s = 0.f;
            #pragma unroll
            for (int c = 0; c < 8; ++c)
                s += tpIn[(((size_t)bt*8 + c)*16 + h)*64 + l];
            size_t oi = ((size_t)bt*16 + h)*64 + l;
            float vs;
            if (MODE == 1){
                float sn = wredsum64(s*s);
                float v1 = s*squash_sc(sn);
                v1buf[oi] = v1;
                float q = v1*sp;
                float sn2 = wredsum64(q*q);
                vs = q*squash_sc(sn2);
            } else {
                float q = v1buf[oi]*s;
                float sn = wredsum64(q*q);
                vs = vsumIn[oi] + q*squash_sc(sn);
            }
            if (MODE != 3) vsumOut[oi] = vs;
            float vo = __shfl_xor(vs, 1, 64);
            if (!(l & 1)) vLp[h*36 + (l >> 1)] = pkrtz(vs, vo);
        }
    }
    __syncthreads();

    // logits -> bL ; thread owns (n = t&127, hg = t>>7 covering 8 h)
    {
        int n = t & 127, hg = t >> 7;
        float acc8[8];
        #pragma unroll
        for (int i = 0; i < 8; ++i) acc8[i] = 0.f;
        if (MODE != 0){
            #pragma unroll
            for (int j = 0; j < 8; ++j){
                uint4 pq = *(uint4*)&PL[n*36 + 4*j];
                #pragma unroll
                for (int i = 0; i < 8; ++i){
                    uint4 vq = *(uint4*)&vLp[(hg*8 + i)*36 + 4*j];
                    acc8[i] = fdot2u(pq.x, vq.x, acc8[i]);
                    acc8[i] = fdot2u(pq.y, vq.y, acc8[i]);
                    acc8[i] = fdot2u(pq.z, vq.z, acc8[i]);
                    acc8[i] = fdot2u(pq.w, vq.w, acc8[i]);
                }
            }
        }
        if (MODE == 0){
            float tl[16];
            #pragma unroll
            for (int e = 0; e < 16; ++e) tl[e] = teb[bt*16 + e];
            #pragma unroll
            for (int i = 0; i < 8; ++i){
                int h = hg*8 + i;
                float s = 0.f;
                #pragma unroll
                for (int e = 0; e < 16; ++e)
                    s += tl[e]*adj[(((e << 4) + h) << 10) + n0 + n];
                acc8[i] = s;
                dadjb[((size_t)bt*16 + h)*1024 + n0 + n] = s;
            }
        }
        if (MODE == 3){
            #pragma unroll
            for (int i = 0; i < 8; ++i)
                acc8[i] += dadjb[((size_t)bt*16 + hg*8 + i)*1024 + n0 + n];
        }
        #pragma unroll
        for (int i = 0; i < 8; ++i) bL[(hg*8 + i)*130 + n] = acc8[i];
    }
    __syncthreads();

    // softmax over h per n
    if (t < 128){
        int n = t;
        float M = -1e30f;
        #pragma unroll
        for (int h = 0; h < 16; ++h) M = fmaxf(M, bL[h*130 + n]);
        float S = 0.f; float ev[16];
        #pragma unroll
        for (int h = 0; h < 16; ++h){ ev[h] = __expf(bL[h*130 + n] - M); S += ev[h]; }
        float inv = 1.f/S;
        #pragma unroll
        for (int h = 0; h < 16; ++h){
            float cv = ev[h]*inv;
            cL[n*20 + h] = cv;
            if (MODE == 3) cout[((size_t)bt*16 + h)*1024 + n0 + n] = cv;
        }
    }
    __syncthreads();

    // partial t[h][d]: wave w -> h 4w..4w+3, lane = d; sumP folded (MODE 0)
    float acc[4] = {0.f,0.f,0.f,0.f};
    float sp2 = 0.f;
    #pragma unroll 2
    for (int n = 0; n < 128; ++n){
        unsigned int pv = PL[n*36 + (l >> 1)];
        float p = (l & 1) ? hiF(pv) : loF(pv);
        float4 c4 = *(float4*)&cL[n*20 + 4*w];
        acc[0] += c4.x*p; acc[1] += c4.y*p; acc[2] += c4.z*p; acc[3] += c4.w*p;
        if (MODE == 0) sp2 += p;
    }
    #pragma unroll
    for (int i = 0; i < 4; ++i)
        tpOut[(((size_t)bt*8 + ch)*16 + 4*w + i)*64 + l] = acc[i];
    if (MODE == 0 && w == 0)
        spOut[((size_t)bt*8 + ch)*64 + l] = sp2;
}

// k_s: s = reduce tpart (raw)   grid 192 x 256
__global__ __launch_bounds__(256) void k_s(const float* __restrict__ tpart,
        float* __restrict__ sout){
    int bt = blockIdx.x;
    int w = threadIdx.x >> 6, l = threadIdx.x & 63;
    #pragma unroll
    for (int i = 0; i < 4; ++i){
        int h = 4*w + i;
        float s = 0.f;
        #pragma unroll
        for (int c = 0; c < 8; ++c)
            s += tpart[(((size_t)bt*8 + c)*16 + h)*64 + l];
        sout[((size_t)bt*16 + h)*64 + l] = s;
    }
}

// k_dyntem: fused dyn + tem.  grid (16,64) x 256
__global__ __launch_bounds__(256) void k_dyntem(const float* __restrict__ timeb,
        const float* __restrict__ tadj, const float* __restrict__ sbuf,
        float* __restrict__ dyn, float* __restrict__ tem){
    __shared__ float dynL[192];
    __shared__ float part[4][64];
    int b = blockIdx.x, h = blockIdx.y, t = threadIdx.x;
    if (t < 192){
        float a = 0.f;
        #pragma unroll
        for (int e = 0; e < 16; ++e)
            a += timeb[b*16 + e]*tadj[((size_t)e*HT_ + h)*TT_ + t];
        dynL[t] = a;
        dyn[((size_t)b*HT_ + h)*TT_ + t] = a;
    }
    __syncthreads();
    int p = t >> 6, d = t & 63;
    const float* sb = sbuf + (size_t)b*TT_*64;
    float a = 0.f;
    #pragma unroll 4
    for (int k = 48*p; k < 48*p + 48; ++k)
        a += dynL[k]*(sb[(size_t)k*64 + d] + (float)((k >> 4) + 1)*(1.f/12.f));
    part[p][d] = a;
    __syncthreads();
    if (t < 64)
        tem[((size_t)b*HT_ + h)*64 + t] =
            lrelu_(part[0][t] + part[1][t] + part[2][t] + part[3][t]);
}

// ret=lrelu(sum_h dyn*tem)+s; v2=squash(ret)   grid (16,48) x 256
__global__ __launch_bounds__(256) void k_retv2(const float* __restrict__ dyn,
        const float* __restrict__ temb, const float* __restrict__ sbuf,
        float* __restrict__ v2){
    int b = blockIdx.x, kg = blockIdx.y;
    int w = threadIdx.x >> 6, l = threadIdx.x & 63;
    int k = kg*4 + w;
    const float* tb = temb + (size_t)b*HT_*64;
    float a0 = 0.f, a1 = 0.f;
    #pragma unroll 4
    for (int h = 0; h < HT_; h += 2){
        a0 += dyn[((size_t)b*HT_ + h  )*TT_ + k] * tb[(size_t)h*64 + l];
        a1 += dyn[((size_t)b*HT_ + h+1)*TT_ + k] * tb[(size_t)(h+1)*64 + l];
    }
    float a = lrelu_(a0 + a1);
    float r = a + sbuf[((size_t)b*TT_ + k)*64 + l];
    float sn = wredsum64(r*r);
    v2[((size_t)b*TT_ + k)*64 + l] = r*squash_sc(sn);
}

// recon f16 pairs, layout [n][bt][32]: rec[n,bt,d] = sum_h c[bt,h,n]*v2[bt,h,d]
// grid (192,8) x 256
__global__ __launch_bounds__(256) void k_rec(const float* __restrict__ cbuf,
        const float* __restrict__ v2, unsigned int* __restrict__ recpk){
    __shared__ float vL[16*68];
    __shared__ float cL[16*132];
    int bt = blockIdx.x, nc = blockIdx.y;
    int t = threadIdx.x, l = t & 63, g = t >> 6;
    #pragma unroll
    for (int i = 0; i < 4; ++i){
        int idx = i*256 + t;
        vL[(idx>>6)*68 + (idx&63)] = v2[(size_t)bt*1024 + idx];
    }
    #pragma unroll
    for (int i = 0; i < 8; ++i){
        int idx = i*256 + t;
        cL[(idx>>7)*132 + (idx&127)] =
            cbuf[((size_t)bt*16 + (idx>>7))*1024 + nc*128 + (idx&127)];
    }
    __syncthreads();
    float vreg[16];
    #pragma unroll
    for (int h = 0; h < 16; ++h) vreg[h] = vL[h*68 + l];
    #pragma unroll 4
    for (int i = 0; i < 32; ++i){
        int nl = g + 4*i;
        float a = 0.f;
        #pragma unroll
        for (int h = 0; h < 16; ++h) a += cL[h*132 + nl]*vreg[h];
        float ap = __shfl_xor(a, 1, 64);
        if (!(l & 1))
            recpk[((size_t)(nc*128 + nl)*192 + bt)*32 + (l>>1)] = pkrtz(a, ap);
    }
}

// out = lrelu(rec @ wsp[n] + bsp[n] + x)   grid (1024,2) x 256
__global__ __launch_bounds__(256) void k_final(const float* __restrict__ x,
        const float* __restrict__ ne, const float* __restrict__ wspa,
        const float* __restrict__ bspa, const unsigned int* __restrict__ recpk,
        float* __restrict__ out){
    __shared__ __align__(16) char uSm[17664];
    float* wspL = (float*)uSm;                       // [64][68]
    float* bspL = (float*)(uSm + 17408);             // [64]
    unsigned int* recL = (unsigned int*)uSm;         // [96][32] (phase B/C)
    int n = blockIdx.x, half = blockIdx.y;
    int t = threadIdx.x, l = t & 63, g = t >> 6;
    float nl16[16];
    #pragma unroll
    for (int e = 0; e < 16; ++e) nl16[e] = ne[n*16 + e];
    #pragma unroll
    for (int j = 0; j < 16; ++j){
        int io = j*256 + t;
        float a = 0.f;
        #pragma unroll
        for (int e = 0; e < 16; ++e) a += nl16[e]*wspa[(size_t)e*4096 + io];
        wspL[(io>>6)*68 + (io&63)] = a;
    }
    if (t < 64){
        float a = 0.f;
        #pragma unroll
        for (int e = 0; e < 16; ++e) a += nl16[e]*bspa[e*64 + t];
        bspL[t] = a;
    }
    __syncthreads();
    unsigned int wr[32];
    #pragma unroll
    for (int ip = 0; ip < 32; ++ip)
        wr[ip] = pkrtz(wspL[(2*ip)*68 + l], wspL[(2*ip+1)*68 + l]);
    float bsp = bspL[l];
    __syncthreads();
    {
        const uint4* src = (const uint4*)(recpk + ((size_t)n*192 + half*96)*32);
        #pragma unroll
        for (int k = 0; k < 3; ++k)
            ((uint4*)recL)[t + 256*k] = src[t + 256*k];
    }
    __syncthreads();
    #pragma unroll 2
    for (int i = 0; i < 24; ++i){
        int r = i*4 + g;
        int bt = half*96 + r;
        const uint4* rp = (const uint4*)&recL[r*32];
        float o0 = bsp, o1 = 0.f;
        #pragma unroll
        for (int jj = 0; jj < 8; ++jj){
            uint4 rq = rp[jj];
            o0 = fdot2u(rq.x, wr[4*jj+0], o0);
            o1 = fdot2u(rq.y, wr[4*jj+1], o1);
            o0 = fdot2u(rq.z, wr[4*jj+2], o0);
            o1 = fdot2u(rq.w, wr[4*jj+3], o1);
        }
        size_t oidx = ((size_t)bt*1024 + n)*64 + l;
        out[oidx] = lrelu_(o0 + o1 + x[oidx]);
    }
}

extern "C" void kernel_launch(void* const* d_in, const int* in_sizes, int n_in,
                              void* d_out, int out_size, void* d_ws, size_t ws_size,
                              hipStream_t stream) {
    const float* x     = (const float*)d_in[0];
    const float* ne    = (const float*)d_in[1];
    const float* timeb = (const float*)d_in[2];
    const float* teb   = (const float*)d_in[3];
    const float* Wp    = (const float*)d_in[4];
    const float* bp    = (const float*)d_in[5];
    const float* tadj  = (const float*)d_in[6];
    const float* adj   = (const float*)d_in[7];
    const float* wspa  = (const float*)d_in[8];
    const float* bspa  = (const float*)d_in[9];

    float* out    = (float*)d_out;
    float* outc   = out  + (size_t)BT_*N_*64;      // c:   [BT,HS,N]
    float* outdyn = outc + (size_t)BT_*HS_*N_;     // dyn: [B,HT,TT]

    char* ws = (char*)d_ws;
    unsigned int* Ppk  = (unsigned int*)ws;                          // 25.2 MB
    float* dadj  = (float*)(ws + 25165824);                          // 12.6 MB
    float* tpA   = dadj  + (size_t)BT_*HS_*N_;                       // 6.3 MB
    float* tpB   = tpA   + (size_t)BT_*8*HS_*64;                     // 6.3 MB
    float* spart = tpB   + (size_t)BT_*8*HS_*64;                     // 0.39 MB
    float* v1buf = spart + (size_t)BT_*8*64;
    float* vs0   = v1buf + (size_t)BT_*HS_*64;
    float* vs1   = vs0   + (size_t)BT_*HS_*64;
    float* sbuf  = vs1   + (size_t)BT_*HS_*64;
    float* temb  = sbuf  + (size_t)BT_*HS_*64;
    float* v2    = temb  + (size_t)B_*HT_*64;
    unsigned int* recpk = (unsigned int*)(v2 + (size_t)BT_*HS_*64);  // 25.2 MB
    unsigned int* Wpk2  = recpk + (size_t)N_*BT_*32;                 // 8 KB

    k_wpack<<<dim3(1), 256, 0, stream>>>(Wp, Wpk2);
    k_P<<<dim3(BT_, 4), 256, 0, stream>>>(x, Wpk2, bp, Ppk);

    // pass 0: logits = dadj (computed inline, stored); t partials + sumP chunks
    kA<0><<<dim3(BT_, 8), 256, 0, stream>>>(Ppk, teb, adj, dadj, nullptr,
            nullptr, nullptr, nullptr, nullptr, tpA, spart, nullptr);
    // iter1(fold)+iter2: prologue {v1, vr1=vs0}; c2; t2 -> tpB
    kA<1><<<dim3(BT_, 8), 256, 0, stream>>>(Ppk, teb, adj, dadj, tpA,
            spart, v1buf, nullptr, vs0, tpB, nullptr, nullptr);
    // iter3: prologue {v2; vs1=vs0+v2}; c3; t3 -> tpA
    kA<2><<<dim3(BT_, 8), 256, 0, stream>>>(Ppk, teb, adj, dadj, tpB,
            nullptr, v1buf, vs0, vs1, tpA, nullptr, nullptr);
    // final: prologue {v3; vs=vs1+v3}; c=softmax(vs.P+dadj) -> outc; s -> tpB
    kA<3><<<dim3(BT_, 8), 256, 0, stream>>>(Ppk, teb, adj, dadj, tpA,
            nullptr, v1buf, vs1, nullptr, tpB, nullptr, outc);
    k_s<<<dim3(BT_), 256, 0, stream>>>(tpB, sbuf);

    k_dyntem<<<dim3(B_, HT_), 256, 0, stream>>>(timeb, tadj, sbuf, outdyn, temb);
    k_retv2<<<dim3(B_, 48), 256, 0, stream>>>(outdyn, temb, sbuf, v2);
    k_rec<<<dim3(BT_, 8), 256, 0, stream>>>(outc, v2, recpk);
    k_final<<<dim3(N_, 2), 256, 0, stream>>>(x, ne, wspa, bspa, recpk, out);
}